// Round 8
// baseline (280.588 us; speedup 1.0000x reference)
//
#include <hip/hip_runtime.h>
#include <hip/hip_bf16.h>

// Problem constants (CrossEncoder): B=4, QT=1024, N=2048, E=512, H=8, Dh=64
#define B_  4
#define QT_ 1024
#define N_  2048
#define E_  512
#define H_  8
#define DH_ 64

typedef float  f32x4  __attribute__((ext_vector_type(4)));
typedef __bf16 bf16x8 __attribute__((ext_vector_type(8)));
typedef unsigned short u16;
typedef u16 u16x4 __attribute__((ext_vector_type(4)));

// round-to-nearest-even f32 -> bf16
static __device__ __forceinline__ u16 f2bf(float f) {
    unsigned u = __builtin_bit_cast(unsigned, f);
    return (u16)((u + 0x7fffu + ((u >> 16) & 1u)) >> 16);
}

static __device__ __forceinline__ bf16x8 ldbf8(const u16* p) {
    uint4 v = *reinterpret_cast<const uint4*>(p);
    return __builtin_bit_cast(bf16x8, v);
}

#define MFMA16(a, b, c) __builtin_amdgcn_mfma_f32_16x16x32_bf16((a), (b), (c), 0, 0, 0)

// async global->LDS, 16B per lane; LDS dest = uniform base + lane*16 (linear)
static __device__ __forceinline__ void g2lds16(const u16* g, u16* l) {
    __builtin_amdgcn_global_load_lds((__attribute__((address_space(1))) void*)(void*)g,
                                     (__attribute__((address_space(3))) void*)l, 16, 0, 0);
}

// -------------------- fused f32 -> bf16 convert (q + kv) --------------------
__global__ __launch_bounds__(256) void cvt_all(const float* __restrict__ q,
                                               const float* __restrict__ kv,
                                               u16* __restrict__ qbf,
                                               u16* __restrict__ kvbf) {
    const int QN4 = B_ * QT_ * E_ / 4;  // 524288
    int i = blockIdx.x * 256 + threadIdx.x;
    const float4* s;
    ushort4* d;
    if (i < QN4) {
        s = reinterpret_cast<const float4*>(q) + i;
        d = reinterpret_cast<ushort4*>(qbf) + i;
    } else {
        int j = i - QN4;
        s = reinterpret_cast<const float4*>(kv) + j;
        d = reinterpret_cast<ushort4*>(kvbf) + j;
    }
    float4 v = *s;
    ushort4 o;
    o.x = f2bf(v.x); o.y = f2bf(v.y); o.z = f2bf(v.z); o.w = f2bf(v.w);
    *d = o;
}

// -------------------- batched weight transpose: wt4[z][n][k] = bf16(Wz[k][n]) ------------
__global__ __launch_bounds__(256) void wt_all(const float* __restrict__ Wq,
                                              const float* __restrict__ Wk,
                                              const float* __restrict__ Wv,
                                              const float* __restrict__ Wo,
                                              u16* __restrict__ wt4) {
    __shared__ float t[64][65];
    const float* W = (blockIdx.z == 0) ? Wq : (blockIdx.z == 1) ? Wk : (blockIdx.z == 2) ? Wv : Wo;
    u16* dst = wt4 + (size_t)blockIdx.z * E_ * E_;
    int k0 = blockIdx.x * 64, n0 = blockIdx.y * 64;
    int tid = threadIdx.x;
#pragma unroll
    for (int i = 0; i < 16; i++) {
        int idx = tid + i * 256, r = idx >> 6, c = idx & 63;
        t[r][c] = W[(k0 + r) * E_ + n0 + c];
    }
    __syncthreads();
#pragma unroll
    for (int i = 0; i < 16; i++) {
        int idx = tid + i * 256, r = idx >> 6, c = idx & 63;
        dst[(n0 + r) * E_ + k0 + c] = f2bf(t[c][r]);
    }
}

// -------------------- fused RoPE tables (reference quirk: freq index = d>>2) ----------
__global__ __launch_bounds__(256) void rope_all(const int* __restrict__ qpos,
                                                const int* __restrict__ kvpos,
                                                float2* __restrict__ tq,
                                                float2* __restrict__ tk) {
    const int QROWS = B_ * QT_;  // 4096
    int i = blockIdx.x * 256 + threadIdx.x;  // 196608 total
    int k = i & 15, row = i >> 4;
    float fr = exp2f((float)k * -0.41524101186092028f);  // log2(10000)/32
    int p;
    float2* dst;
    if (row < QROWS) { p = qpos[row]; dst = tq + i; }
    else { p = kvpos[row - QROWS]; dst = tk + (i - QROWS * 16); }
    float sn, cs;
    sincosf((float)p * fr, &sn, &cs);
    *dst = make_float2(cs, sn);
}

// -------------------- fused Q+K+V projection GEMM (BK=32: 32KB LDS, all 640 resident) ----
// 640 blocks: 128 Q-role (M=4096,N=512) + 512 KV-role (M=8192,N=1024 fused K|V).
// Q epilogue: RoPE * 0.125 -> qhh [B,H,QT,64]; K: RoPE -> khh; V: tiled vt [bh][n/64][d][64]
__global__ __launch_bounds__(256) void proj_qkv(const u16* __restrict__ qbf,
                                                const u16* __restrict__ kvbf,
                                                const u16* __restrict__ wt4,
                                                const float* __restrict__ bq,
                                                const float* __restrict__ bk,
                                                const float* __restrict__ bv,
                                                u16* __restrict__ qhh,
                                                u16* __restrict__ khh,
                                                u16* __restrict__ vt,
                                                const float2* __restrict__ tq,
                                                const float2* __restrict__ tk) {
    __shared__ __align__(16) u16 la[2][128 * 32];
    __shared__ __align__(16) u16 lb[2][128 * 32];

    const int id = blockIdx.x;
    const int sw = (id & 7) * 80 + (id >> 3);  // bijective XCD swizzle over 640
    const bool isQ = (sw < 128);
    int m0, n0;
    const u16 *X, *W;
    if (isQ) { m0 = (sw >> 2) * 128; n0 = (sw & 3) * 128; X = qbf; W = wt4; }
    else { const int s2 = sw - 128; m0 = (s2 >> 3) * 128; n0 = (s2 & 7) * 128; X = kvbf; W = wt4 + 512 * 512; }

    const int tid = threadIdx.x, w = tid >> 6, lane = tid & 63;
    const int lr = lane & 15, lg = lane >> 4;
    const int wml = (w >> 1) * 64, wnl = (w & 1) * 64;

    auto stage = [&](const u16* gsrc, u16* lbuf) {
#pragma unroll
        for (int i = 0; i < 2; i++) {
            const int r0 = w * 32 + i * 16;
            const int row = r0 + (lane >> 2);
            const u16* src = gsrc + row * E_ + (((lane & 3) ^ (row & 3)) * 8);
            g2lds16(src, lbuf + r0 * 32);
        }
    };

    f32x4 acc[4][4];
#pragma unroll
    for (int i = 0; i < 4; i++)
#pragma unroll
        for (int j = 0; j < 4; j++) acc[i][j] = f32x4{0.f, 0.f, 0.f, 0.f};

    stage(X + m0 * E_, la[0]);
    stage(W + n0 * E_, lb[0]);
    __syncthreads();
    int buf = 0;
    for (int kt = 0; kt < E_ / 32; kt++) {
        if (kt + 1 < E_ / 32) {
            stage(X + m0 * E_ + (kt + 1) * 32, la[buf ^ 1]);
            stage(W + n0 * E_ + (kt + 1) * 32, lb[buf ^ 1]);
        }
        bf16x8 a[4], bb[4];
#pragma unroll
        for (int mb = 0; mb < 4; mb++) {
            const int r = wml + mb * 16 + lr;
            a[mb] = ldbf8(la[buf] + r * 32 + ((lg ^ (r & 3)) * 8));
        }
#pragma unroll
        for (int nb = 0; nb < 4; nb++) {
            const int r = wnl + nb * 16 + lr;
            bb[nb] = ldbf8(lb[buf] + r * 32 + ((lg ^ (r & 3)) * 8));
        }
        __builtin_amdgcn_s_setprio(1);
#pragma unroll
        for (int mb = 0; mb < 4; mb++)
#pragma unroll
            for (int nb = 0; nb < 4; nb++)
                acc[mb][nb] = MFMA16(a[mb], bb[nb], acc[mb][nb]);
        __builtin_amdgcn_s_setprio(0);
        __syncthreads();
        buf ^= 1;
    }

    const bool isV = !isQ && (n0 >= 512);  // wg-uniform
#pragma unroll
    for (int mb = 0; mb < 4; mb++) {
#pragma unroll
        for (int nb = 0; nb < 4; nb++) {
            const int col = n0 + wnl + nb * 16 + lr;  // C col = lane&15
            const float bs = isQ ? bq[col] : (isV ? bv[col - 512] : bk[col]);
#pragma unroll
            for (int r = 0; r < 4; r++) {
                const int row = m0 + wml + mb * 16 + lg * 4 + r;  // C row = (lane>>4)*4+reg
                float v = acc[mb][nb][r] + bs;
                if (isV) {
                    const int cv = col - 512, d = cv & 63, h = cv >> 6;
                    const int b = row >> 11, n = row & 2047;
                    vt[(((b * H_ + h) * (N_ / 64) + (n >> 6)) * DH_ + d) * 64 + (n & 63)] = f2bf(v);
                } else {
                    const int d = col & 63, h = col >> 6;
                    float2 t = isQ ? tq[row * 16 + (d >> 2)] : tk[row * 16 + (d >> 2)];
                    float other = __shfl_xor(v, 1);  // pair mate: col^1 lives in lane^1
                    float y = (d & 1) ? (other * t.y + v * t.x) : (v * t.x - other * t.y);
                    if (isQ) {
                        y *= 0.125f;  // softmax scale folded into Q
                        const int b = row >> 10, tok = row & 1023;
                        qhh[((b * H_ + h) * QT_ + tok) * DH_ + d] = f2bf(y);
                    } else {
                        const int b = row >> 11, tok = row & 2047;
                        khh[((b * H_ + h) * N_ + tok) * DH_ + d] = f2bf(y);
                    }
                }
            }
        }
    }
}

// -------------------- attn pass A: partial row sums of exp(score) --------------------
// grid 2048 (XCD-swizzled): (bh, qt, ns). wg = 64 q x 512 kv. NO LDS, NO barriers:
// K is L2-resident per XCD (~1MB < 4MB) - direct b128 reads; TLP (32 waves/CU) hides L2.
__global__ __launch_bounds__(256, 8) void attn_sums(const u16* __restrict__ qh,
                                                    const u16* __restrict__ kh,
                                                    const int* __restrict__ kv_mask,
                                                    float* __restrict__ sums4) {
    const int id = blockIdx.x;
    const int sw = (id & 7) * 256 + (id >> 3);  // XCD k gets 4 consecutive bh
    const int bh = sw >> 6, qt = (sw >> 2) & 15, ns = sw & 3;
    const int b = bh >> 3;
    const int tid = threadIdx.x, w = tid >> 6, lane = tid & 63;
    const int lr = lane & 15, lg = lane >> 4;
    const int q0 = qt * 64 + w * 16;

    const u16* qbase = qh + (bh * QT_ + q0) * DH_;
    const bf16x8 qf0 = ldbf8(qbase + lr * DH_ + lg * 8);   // Q pre-scaled by 0.125
    const bf16x8 qf1 = ldbf8(qbase + lr * DH_ + 32 + lg * 8);
    const u16* kbase = kh + (size_t)bh * (N_ * DH_) + ns * 512 * DH_;
    const int* mbase = kv_mask + b * N_ + ns * 512;

    float lsum[4] = {0.f, 0.f, 0.f, 0.f};
    for (int kb = 0; kb < 32; kb++) {
        const int krow = kb * 16 + lr;
        bf16x8 k0 = ldbf8(kbase + krow * DH_ + lg * 8);
        bf16x8 k1 = ldbf8(kbase + krow * DH_ + 32 + lg * 8);
        f32x4 c = f32x4{0.f, 0.f, 0.f, 0.f};
        __builtin_amdgcn_s_setprio(1);
        c = MFMA16(qf0, k0, c);
        c = MFMA16(qf1, k1, c);
        __builtin_amdgcn_s_setprio(0);
        const bool keep = (mbase[krow] != 0);
#pragma unroll
        for (int r = 0; r < 4; r++) lsum[r] += keep ? __expf(c[r]) : 0.f;
    }
#pragma unroll
    for (int r = 0; r < 4; r++) {
        float s = lsum[r];
        s += __shfl_xor(s, 1); s += __shfl_xor(s, 2);
        s += __shfl_xor(s, 4); s += __shfl_xor(s, 8);
        if (lr == 0) sums4[((size_t)bh * QT_ + q0 + lg * 4 + r) * 4 + ns] = s;
    }
}

// -------------------- attn pass B: write attn + partial PV --------------------
// grid 2048 (XCD-swizzled): (bh, qt, ns of 4). wg = 64 q x 512 kv (8 tiles of 64).
// NO K/V LDS staging (L2-resident, direct b128 reads), NO barriers (P tile is per-wave).
// LDS = 8KB packed-P only. Occupancy: VGPR-capped ~6 waves/SIMD via launch_bounds.
__global__ __launch_bounds__(256, 6) void attn_pv(const u16* __restrict__ qh,
                                                  const u16* __restrict__ kh,
                                                  const u16* __restrict__ vt,
                                                  const int* __restrict__ kv_mask,
                                                  const float* __restrict__ sums4,
                                                  float* __restrict__ attn_out,
                                                  float* __restrict__ pvpart) {
    __shared__ unsigned PW[4][16][32];  // per-wave packed bf16-pair P, granule-swizzled

    const int id = blockIdx.x;
    const int sw = (id & 7) * 256 + (id >> 3);  // XCD k gets 4 consecutive bh
    const int bh = sw >> 6, qt = (sw >> 2) & 15, ns = sw & 3;
    const int b = bh >> 3;
    const int tid = threadIdx.x, w = tid >> 6, lane = tid & 63;
    const int lr = lane & 15, lg = lane >> 4;
    const int q0 = qt * 64 + w * 16;

    const u16* qbase = qh + (bh * QT_ + q0) * DH_;
    const bf16x8 qf0 = ldbf8(qbase + lr * DH_ + lg * 8);   // Q pre-scaled by 0.125
    const bf16x8 qf1 = ldbf8(qbase + lr * DH_ + 32 + lg * 8);
    const u16* kbase = kh + (size_t)bh * (N_ * DH_) + ns * 512 * DH_;
    const u16* vbase = vt + (size_t)bh * (N_ * DH_) + ns * 512 * DH_;  // tiled [t][64d][64]
    const int* mbase = kv_mask + b * N_ + ns * 512;

    // total row sums -> inv
    float inv[4];
#pragma unroll
    for (int r = 0; r < 4; r++) {
        float4 s4 = *reinterpret_cast<const float4*>(
            sums4 + ((size_t)bh * QT_ + q0 + lg * 4 + r) * 4);
        float tot = s4.x + s4.y + s4.z + s4.w;
        inv[r] = (tot > 0.f) ? (1.0f / tot) : 0.f;  // all-masked row -> attn = ctx = 0
    }

    f32x4 pv[4];
#pragma unroll
    for (int i = 0; i < 4; i++) pv[i] = f32x4{0.f, 0.f, 0.f, 0.f};
    unsigned(*P)[32] = PW[w];
    float* abase = attn_out + ((size_t)(bh * QT_ + q0)) * N_ + ns * 512;
    const int srow = lane >> 4, cq = lane & 15;  // store: 4 rows x 256B per instr

    for (int t = 0; t < 8; t++) {
#pragma unroll
        for (int n = 0; n < 4; n++) {
            const int krow = t * 64 + n * 16 + lr;
            bf16x8 k0 = ldbf8(kbase + krow * DH_ + lg * 8);
            bf16x8 k1 = ldbf8(kbase + krow * DH_ + 32 + lg * 8);
            f32x4 c = f32x4{0.f, 0.f, 0.f, 0.f};
            __builtin_amdgcn_s_setprio(1);
            c = MFMA16(qf0, k0, c);
            c = MFMA16(qf1, k1, c);
            __builtin_amdgcn_s_setprio(0);
            const bool keep = (mbase[krow] != 0);
#pragma unroll
            for (int r = 0; r < 4; r++) {
                float p = keep ? (__expf(c[r]) * inv[r]) : 0.f;  // normalized
                float hi = __shfl_xor(p, 1);
                __bf16 lo_b = (__bf16)p, hi_b = (__bf16)hi;
                unsigned pk = ((unsigned)__builtin_bit_cast(u16, hi_b) << 16) |
                              (unsigned)__builtin_bit_cast(u16, lo_b);
                if (!(lr & 1)) {
                    const int row = lg * 4 + r, c32 = n * 8 + (lr >> 1);
                    P[row][(((c32 >> 2) ^ (row & 7)) << 2) + (c32 & 3)] = pk;
                }
            }
        }
        // attn stores: read packed P (b64), unpack bf16->f32, 4 rows x 256B segments
#pragma unroll
        for (int i = 0; i < 4; i++) {
            const int row = i * 4 + srow, rw = row & 7;
            const int m = (((cq >> 1) ^ rw) << 2) + ((cq & 1) << 1);
            uint2 pp = *reinterpret_cast<const uint2*>(&P[row][m]);
            f32x4 vv;
            vv[0] = __builtin_bit_cast(float, pp.x << 16);
            vv[1] = __builtin_bit_cast(float, pp.x & 0xffff0000u);
            vv[2] = __builtin_bit_cast(float, pp.y << 16);
            vv[3] = __builtin_bit_cast(float, pp.y & 0xffff0000u);
            *reinterpret_cast<f32x4*>(abase + (size_t)row * N_ + t * 64 + cq * 4) = vv;
        }
        // PV: ctx[16q,64d] += P @ V-tile; A-frag = one swizzled b128 granule; V direct b128
#pragma unroll
        for (int ks = 0; ks < 2; ks++) {
            const int g = (4 * ks + lg) ^ (lr & 7);
            uint4 a4 = *reinterpret_cast<const uint4*>(&P[lr][g << 2]);
            bf16x8 af = __builtin_bit_cast(bf16x8, a4);
            __builtin_amdgcn_s_setprio(1);
#pragma unroll
            for (int nb = 0; nb < 4; nb++) {
                const int vrow = t * 64 + nb * 16 + lr;  // [tile][d][64] linear
                bf16x8 bv = ldbf8(vbase + vrow * 64 + ks * 32 + lg * 8);
                pv[nb] = MFMA16(af, bv, pv[nb]);
            }
            __builtin_amdgcn_s_setprio(0);
        }
    }

    // partial ctx: pvpart[ns][bh][q][64]
    float* pbase = pvpart + (((size_t)ns * 32 + bh) * QT_) * DH_;
#pragma unroll
    for (int nb = 0; nb < 4; nb++)
#pragma unroll
        for (int r = 0; r < 4; r++)
            pbase[(size_t)(q0 + lg * 4 + r) * DH_ + nb * 16 + lr] = pv[nb][r];
}

// -------------------- ctx reduce: ctx[b,tok,h*64+d] = bf16(sum_ns pvpart) ------------
__global__ __launch_bounds__(256) void ctx_reduce(const float* __restrict__ pvpart,
                                                  u16* __restrict__ ctx) {
    const size_t SL = (size_t)32 * QT_ * DH_;  // slice stride (f32)
    const int i = blockIdx.x * 256 + threadIdx.x;  // 524288 threads, 4 elems each
    const int base = i * 4;
    const int d = base & 63, h = (base >> 6) & 7;
    const int bt = base >> 9;              // b*1024 + tok
    const size_t pi = (((size_t)(bt >> 10) * 8 + h) * QT_ + (bt & 1023)) * DH_ + d;
    f32x4 s0 = *reinterpret_cast<const f32x4*>(pvpart + pi);
    f32x4 s1 = *reinterpret_cast<const f32x4*>(pvpart + SL + pi);
    f32x4 s2 = *reinterpret_cast<const f32x4*>(pvpart + 2 * SL + pi);
    f32x4 s3 = *reinterpret_cast<const f32x4*>(pvpart + 3 * SL + pi);
    u16x4 o;
#pragma unroll
    for (int j = 0; j < 4; j++) o[j] = f2bf((s0[j] + s1[j]) + (s2[j] + s3[j]));
    *reinterpret_cast<u16x4*>(ctx + base) = o;
}

// -------------------- O projection: 64x64 tiles, grid 512 --------------------
__global__ __launch_bounds__(256) void proj_o(const u16* __restrict__ X,
                                              const u16* __restrict__ Wt,
                                              const float* __restrict__ bias,
                                              float* __restrict__ outp,
                                              const int* __restrict__ qmask) {
    __shared__ __align__(16) u16 la[2][64 * 64];
    __shared__ __align__(16) u16 lb[2][64 * 64];

    const int id = blockIdx.x;             // 512 blocks
    const int sw = (id & 7) * 64 + (id >> 3);
    const int m0 = (sw >> 3) * 64, n0 = (sw & 7) * 64;

    const int tid = threadIdx.x, w = tid >> 6, lane = tid & 63;
    const int lr = lane & 15, lg = lane >> 4;
    const int wml = (w >> 1) * 32, wnl = (w & 1) * 32;

    auto stage = [&](const u16* gsrc, u16* lbuf) {
#pragma unroll
        for (int i = 0; i < 2; i++) {
            const int r0 = w * 16 + i * 8;
            const int row = r0 + (lane >> 3);
            const u16* src = gsrc + row * E_ + (((lane & 7) ^ (row & 7)) * 8);
            g2lds16(src, lbuf + r0 * 64);
        }
    };

    f32x4 acc[2][2];
#pragma unroll
    for (int i = 0; i < 2; i++)
#pragma unroll
        for (int j = 0; j < 2; j++) acc[i][j] = f32x4{0.f, 0.f, 0.f, 0.f};

    stage(X + m0 * E_, la[0]);
    stage(Wt + n0 * E_, lb[0]);
    __syncthreads();
    int buf = 0;
    for (int kt = 0; kt < E_ / 64; kt++) {
        if (kt + 1 < E_ / 64) {
            stage(X + m0 * E_ + (kt + 1) * 64, la[buf ^ 1]);
            stage(Wt + n0 * E_ + (kt + 1) * 64, lb[buf ^ 1]);
        }
#pragma unroll
        for (int ks = 0; ks < 2; ks++) {
            bf16x8 a[2], bb[2];
#pragma unroll
            for (int mb = 0; mb < 2; mb++) {
                const int r = wml + mb * 16 + lr;
                a[mb] = ldbf8(la[buf] + r * 64 + (((ks * 4 + lg) ^ (r & 7)) * 8));
            }
#pragma unroll
            for (int nb = 0; nb < 2; nb++) {
                const int r = wnl + nb * 16 + lr;
                bb[nb] = ldbf8(lb[buf] + r * 64 + (((ks * 4 + lg) ^ (r & 7)) * 8));
            }
            __builtin_amdgcn_s_setprio(1);
#pragma unroll
            for (int mb = 0; mb < 2; mb++)
#pragma unroll
                for (int nb = 0; nb < 2; nb++)
                    acc[mb][nb] = MFMA16(a[mb], bb[nb], acc[mb][nb]);
            __builtin_amdgcn_s_setprio(0);
        }
        __syncthreads();
        buf ^= 1;
    }

#pragma unroll
    for (int mb = 0; mb < 2; mb++) {
#pragma unroll
        for (int nb = 0; nb < 2; nb++) {
            const int col = n0 + wnl + nb * 16 + lr;
            const float bs = bias[col];
#pragma unroll
            for (int r = 0; r < 4; r++) {
                const int row = m0 + wml + mb * 16 + lg * 4 + r;
                float v = acc[mb][nb][r] + bs;
                float m = (qmask[row] != 0) ? 1.0f : 0.0f;
                outp[row * E_ + col] = v * m;
            }
        }
    }
}

// -------------------- host launch --------------------
extern "C" void kernel_launch(void* const* d_in, const int* in_sizes, int n_in,
                              void* d_out, int out_size, void* d_ws, size_t ws_size,
                              hipStream_t stream) {
    (void)in_sizes; (void)n_in; (void)out_size; (void)ws_size;
    const float* q   = (const float*)d_in[0];
    const float* kv  = (const float*)d_in[1];
    const int* q_mask  = (const int*)d_in[2];
    const int* kv_mask = (const int*)d_in[3];
    const int* q_pos   = (const int*)d_in[4];
    const int* kv_pos  = (const int*)d_in[5];
    const float* Wq = (const float*)d_in[6];  const float* bq = (const float*)d_in[7];
    const float* Wk = (const float*)d_in[8];  const float* bk = (const float*)d_in[9];
    const float* Wv = (const float*)d_in[10]; const float* bv = (const float*)d_in[11];
    const float* Wo = (const float*)d_in[12]; const float* bo = (const float*)d_in[13];
    float* outp = (float*)d_out;

    char* ws = (char*)d_ws;
    size_t off = 0;
    auto carve = [&](size_t bytes) -> void* {
        void* p = ws + off;
        off = (off + bytes + 255) & ~(size_t)255;
        return p;
    };
    u16* qbf    = (u16*)carve((size_t)B_ * QT_ * E_ * 2);
    u16* kvbf   = (u16*)carve((size_t)B_ * N_ * E_ * 2);
    u16* wt4    = (u16*)carve((size_t)4 * E_ * E_ * 2);  // [Wq^T|Wk^T|Wv^T|Wo^T]
    u16* qhh    = (u16*)carve((size_t)B_ * H_ * QT_ * DH_ * 2);
    u16* khh    = (u16*)carve((size_t)B_ * H_ * N_ * DH_ * 2);
    u16* vt     = (u16*)carve((size_t)B_ * H_ * DH_ * N_ * 2);  // tiled [bh][32][64][64]
    u16* ctx    = (u16*)carve((size_t)B_ * QT_ * E_ * 2);
    float2* tq  = (float2*)carve((size_t)B_ * QT_ * 16 * sizeof(float2));
    float2* tk  = (float2*)carve((size_t)B_ * N_ * 16 * sizeof(float2));
    float* sums4  = (float*)carve((size_t)B_ * H_ * QT_ * 4 * sizeof(float));
    float* pvpart = (float*)carve((size_t)4 * B_ * H_ * QT_ * DH_ * sizeof(float));

    cvt_all<<<6144, 256, 0, stream>>>(q, kv, qbf, kvbf);
    wt_all<<<dim3(8, 8, 4), 256, 0, stream>>>(Wq, Wk, Wv, Wo, wt4);
    rope_all<<<768, 256, 0, stream>>>(q_pos, kv_pos, tq, tk);

    proj_qkv<<<640, 256, 0, stream>>>(qbf, kvbf, wt4, bq, bk, bv, qhh, khh, vt, tq, tk);

    attn_sums<<<2048, 256, 0, stream>>>(qhh, khh, kv_mask, sums4);
    attn_pv<<<2048, 256, 0, stream>>>(qhh, khh, vt, kv_mask, sums4,
                                      outp + (size_t)B_ * QT_ * E_, pvpart);
    ctx_reduce<<<2048, 256, 0, stream>>>(pvpart, ctx);

    proj_o<<<512, 256, 0, stream>>>(ctx, wt4 + 3 * 512 * 512, bo, outp, q_mask);
}

// Round 9
// 216.090 us; speedup vs baseline: 1.2985x; 1.2985x over previous
//
#include <hip/hip_runtime.h>
#include <hip/hip_bf16.h>

// Problem constants (CrossEncoder): B=4, QT=1024, N=2048, E=512, H=8, Dh=64
#define B_  4
#define QT_ 1024
#define N_  2048
#define E_  512
#define H_  8
#define DH_ 64

typedef float  f32x4  __attribute__((ext_vector_type(4)));
typedef __bf16 bf16x8 __attribute__((ext_vector_type(8)));
typedef unsigned short u16;
typedef u16 u16x4 __attribute__((ext_vector_type(4)));

// round-to-nearest-even f32 -> bf16
static __device__ __forceinline__ u16 f2bf(float f) {
    unsigned u = __builtin_bit_cast(unsigned, f);
    return (u16)((u + 0x7fffu + ((u >> 16) & 1u)) >> 16);
}

static __device__ __forceinline__ bf16x8 ldbf8(const u16* p) {
    uint4 v = *reinterpret_cast<const uint4*>(p);
    return __builtin_bit_cast(bf16x8, v);
}

#define MFMA16(a, b, c) __builtin_amdgcn_mfma_f32_16x16x32_bf16((a), (b), (c), 0, 0, 0)

// async global->LDS, 16B per lane; LDS dest = uniform base + lane*16 (linear)
static __device__ __forceinline__ void g2lds16(const u16* g, u16* l) {
    __builtin_amdgcn_global_load_lds((__attribute__((address_space(1))) void*)(void*)g,
                                     (__attribute__((address_space(3))) void*)l, 16, 0, 0);
}

// -------------------- fused f32 -> bf16 convert (q + kv) --------------------
__global__ __launch_bounds__(256) void cvt_all(const float* __restrict__ q,
                                               const float* __restrict__ kv,
                                               u16* __restrict__ qbf,
                                               u16* __restrict__ kvbf) {
    const int QN4 = B_ * QT_ * E_ / 4;  // 524288
    int i = blockIdx.x * 256 + threadIdx.x;
    const float4* s;
    ushort4* d;
    if (i < QN4) {
        s = reinterpret_cast<const float4*>(q) + i;
        d = reinterpret_cast<ushort4*>(qbf) + i;
    } else {
        int j = i - QN4;
        s = reinterpret_cast<const float4*>(kv) + j;
        d = reinterpret_cast<ushort4*>(kvbf) + j;
    }
    float4 v = *s;
    ushort4 o;
    o.x = f2bf(v.x); o.y = f2bf(v.y); o.z = f2bf(v.z); o.w = f2bf(v.w);
    *d = o;
}

// -------------------- batched weight transpose: wt4[z][n][k] = bf16(Wz[k][n]) ------------
__global__ __launch_bounds__(256) void wt_all(const float* __restrict__ Wq,
                                              const float* __restrict__ Wk,
                                              const float* __restrict__ Wv,
                                              const float* __restrict__ Wo,
                                              u16* __restrict__ wt4) {
    __shared__ float t[64][65];
    const float* W = (blockIdx.z == 0) ? Wq : (blockIdx.z == 1) ? Wk : (blockIdx.z == 2) ? Wv : Wo;
    u16* dst = wt4 + (size_t)blockIdx.z * E_ * E_;
    int k0 = blockIdx.x * 64, n0 = blockIdx.y * 64;
    int tid = threadIdx.x;
#pragma unroll
    for (int i = 0; i < 16; i++) {
        int idx = tid + i * 256, r = idx >> 6, c = idx & 63;
        t[r][c] = W[(k0 + r) * E_ + n0 + c];
    }
    __syncthreads();
#pragma unroll
    for (int i = 0; i < 16; i++) {
        int idx = tid + i * 256, r = idx >> 6, c = idx & 63;
        dst[(n0 + r) * E_ + k0 + c] = f2bf(t[c][r]);
    }
}

// -------------------- fused RoPE tables (reference quirk: freq index = d>>2) ----------
__global__ __launch_bounds__(256) void rope_all(const int* __restrict__ qpos,
                                                const int* __restrict__ kvpos,
                                                float2* __restrict__ tq,
                                                float2* __restrict__ tk) {
    const int QROWS = B_ * QT_;  // 4096
    int i = blockIdx.x * 256 + threadIdx.x;  // 196608 total
    int k = i & 15, row = i >> 4;
    float fr = exp2f((float)k * -0.41524101186092028f);  // log2(10000)/32
    int p;
    float2* dst;
    if (row < QROWS) { p = qpos[row]; dst = tq + i; }
    else { p = kvpos[row - QROWS]; dst = tk + (i - QROWS * 16); }
    float sn, cs;
    sincosf((float)p * fr, &sn, &cs);
    *dst = make_float2(cs, sn);
}

// -------------------- fused Q+K+V projection GEMM (BK=32: 32KB LDS, all 640 resident) ----
// 640 blocks: 128 Q-role (M=4096,N=512) + 512 KV-role (M=8192,N=1024 fused K|V).
// Q epilogue: RoPE * 0.125 -> qhh [B,H,QT,64]; K: RoPE -> khh; V: tiled vt [bh][n/64][d][64]
__global__ __launch_bounds__(256) void proj_qkv(const u16* __restrict__ qbf,
                                                const u16* __restrict__ kvbf,
                                                const u16* __restrict__ wt4,
                                                const float* __restrict__ bq,
                                                const float* __restrict__ bk,
                                                const float* __restrict__ bv,
                                                u16* __restrict__ qhh,
                                                u16* __restrict__ khh,
                                                u16* __restrict__ vt,
                                                const float2* __restrict__ tq,
                                                const float2* __restrict__ tk) {
    __shared__ __align__(16) u16 la[2][128 * 32];
    __shared__ __align__(16) u16 lb[2][128 * 32];

    const int id = blockIdx.x;
    const int sw = (id & 7) * 80 + (id >> 3);  // bijective XCD swizzle over 640
    const bool isQ = (sw < 128);
    int m0, n0;
    const u16 *X, *W;
    if (isQ) { m0 = (sw >> 2) * 128; n0 = (sw & 3) * 128; X = qbf; W = wt4; }
    else { const int s2 = sw - 128; m0 = (s2 >> 3) * 128; n0 = (s2 & 7) * 128; X = kvbf; W = wt4 + 512 * 512; }

    const int tid = threadIdx.x, w = tid >> 6, lane = tid & 63;
    const int lr = lane & 15, lg = lane >> 4;
    const int wml = (w >> 1) * 64, wnl = (w & 1) * 64;

    auto stage = [&](const u16* gsrc, u16* lbuf) {
#pragma unroll
        for (int i = 0; i < 2; i++) {
            const int r0 = w * 32 + i * 16;
            const int row = r0 + (lane >> 2);
            const u16* src = gsrc + row * E_ + (((lane & 3) ^ (row & 3)) * 8);
            g2lds16(src, lbuf + r0 * 32);
        }
    };

    f32x4 acc[4][4];
#pragma unroll
    for (int i = 0; i < 4; i++)
#pragma unroll
        for (int j = 0; j < 4; j++) acc[i][j] = f32x4{0.f, 0.f, 0.f, 0.f};

    stage(X + m0 * E_, la[0]);
    stage(W + n0 * E_, lb[0]);
    __syncthreads();
    int buf = 0;
    for (int kt = 0; kt < E_ / 32; kt++) {
        if (kt + 1 < E_ / 32) {
            stage(X + m0 * E_ + (kt + 1) * 32, la[buf ^ 1]);
            stage(W + n0 * E_ + (kt + 1) * 32, lb[buf ^ 1]);
        }
        bf16x8 a[4], bb[4];
#pragma unroll
        for (int mb = 0; mb < 4; mb++) {
            const int r = wml + mb * 16 + lr;
            a[mb] = ldbf8(la[buf] + r * 32 + ((lg ^ (r & 3)) * 8));
        }
#pragma unroll
        for (int nb = 0; nb < 4; nb++) {
            const int r = wnl + nb * 16 + lr;
            bb[nb] = ldbf8(lb[buf] + r * 32 + ((lg ^ (r & 3)) * 8));
        }
        __builtin_amdgcn_s_setprio(1);
#pragma unroll
        for (int mb = 0; mb < 4; mb++)
#pragma unroll
            for (int nb = 0; nb < 4; nb++)
                acc[mb][nb] = MFMA16(a[mb], bb[nb], acc[mb][nb]);
        __builtin_amdgcn_s_setprio(0);
        __syncthreads();
        buf ^= 1;
    }

    const bool isV = !isQ && (n0 >= 512);  // wg-uniform
#pragma unroll
    for (int mb = 0; mb < 4; mb++) {
#pragma unroll
        for (int nb = 0; nb < 4; nb++) {
            const int col = n0 + wnl + nb * 16 + lr;  // C col = lane&15
            const float bs = isQ ? bq[col] : (isV ? bv[col - 512] : bk[col]);
#pragma unroll
            for (int r = 0; r < 4; r++) {
                const int row = m0 + wml + mb * 16 + lg * 4 + r;  // C row = (lane>>4)*4+reg
                float v = acc[mb][nb][r] + bs;
                if (isV) {
                    const int cv = col - 512, d = cv & 63, h = cv >> 6;
                    const int b = row >> 11, n = row & 2047;
                    vt[(((b * H_ + h) * (N_ / 64) + (n >> 6)) * DH_ + d) * 64 + (n & 63)] = f2bf(v);
                } else {
                    const int d = col & 63, h = col >> 6;
                    float2 t = isQ ? tq[row * 16 + (d >> 2)] : tk[row * 16 + (d >> 2)];
                    float other = __shfl_xor(v, 1);  // pair mate: col^1 lives in lane^1
                    float y = (d & 1) ? (other * t.y + v * t.x) : (v * t.x - other * t.y);
                    if (isQ) {
                        y *= 0.125f;  // softmax scale folded into Q
                        const int b = row >> 10, tok = row & 1023;
                        qhh[((b * H_ + h) * QT_ + tok) * DH_ + d] = f2bf(y);
                    } else {
                        const int b = row >> 11, tok = row & 2047;
                        khh[((b * H_ + h) * N_ + tok) * DH_ + d] = f2bf(y);
                    }
                }
            }
        }
    }
}

// -------------------- attn pass A: partial row sums of exp(score) (R7 staged) ----------
// grid 2048 (XCD-swizzled): (bh, qt, ns). wg = 64 q (4 waves x 16) x 512 kv (8 tiles).
// K staged via global_load_lds (dbuf 16KB) - prefetch pipeline. Writes sums4[..*4+ns].
__global__ __launch_bounds__(256) void attn_sums(const u16* __restrict__ qh,
                                                 const u16* __restrict__ kh,
                                                 const int* __restrict__ kv_mask,
                                                 float* __restrict__ sums4) {
    __shared__ __align__(16) u16 kbuf[2][64 * 64];

    const int id = blockIdx.x;
    const int sw = (id & 7) * 256 + (id >> 3);  // XCD k gets 4 consecutive bh
    const int bh = sw >> 6, qt = (sw >> 2) & 15, ns = sw & 3;
    const int b = bh >> 3;
    const int tid = threadIdx.x, w = tid >> 6, lane = tid & 63;
    const int lr = lane & 15, lg = lane >> 4;
    const int q0 = qt * 64 + w * 16;

    const u16* qbase = qh + (bh * QT_ + q0) * DH_;
    const bf16x8 qf0 = ldbf8(qbase + lr * DH_ + lg * 8);   // Q pre-scaled by 0.125
    const bf16x8 qf1 = ldbf8(qbase + lr * DH_ + 32 + lg * 8);
    const u16* kbase = kh + (size_t)bh * (N_ * DH_) + ns * 512 * DH_;
    const int* mbase = kv_mask + b * N_ + ns * 512;

    auto stage = [&](const u16* gsrc, u16* lbuf) {
#pragma unroll
        for (int i = 0; i < 2; i++) {
            const int r0 = w * 16 + i * 8;
            const int row = r0 + (lane >> 3);
            const u16* src = gsrc + row * 64 + (((lane & 7) ^ (row & 7)) * 8);
            g2lds16(src, lbuf + r0 * 64);
        }
    };

    float lsum[4] = {0.f, 0.f, 0.f, 0.f};
    stage(kbase, kbuf[0]);
    __syncthreads();
    for (int t = 0; t < 8; t++) {
        const u16* kc = kbuf[t & 1];
        if (t < 7) stage(kbase + (t + 1) * (64 * DH_), kbuf[(t + 1) & 1]);
#pragma unroll
        for (int n = 0; n < 4; n++) {
            const int krow = n * 16 + lr;
            const u16* kp = kc + krow * 64;
            bf16x8 k0 = ldbf8(kp + ((lg ^ (krow & 7)) * 8));
            bf16x8 k1 = ldbf8(kp + (((lg + 4) ^ (krow & 7)) * 8));
            f32x4 c = f32x4{0.f, 0.f, 0.f, 0.f};
            __builtin_amdgcn_s_setprio(1);
            c = MFMA16(qf0, k0, c);
            c = MFMA16(qf1, k1, c);
            __builtin_amdgcn_s_setprio(0);
            const bool keep = (mbase[t * 64 + n * 16 + lr] != 0);
#pragma unroll
            for (int r = 0; r < 4; r++) lsum[r] += keep ? __expf(c[r]) : 0.f;
        }
        __syncthreads();
    }
#pragma unroll
    for (int r = 0; r < 4; r++) {
        float s = lsum[r];
        s += __shfl_xor(s, 1); s += __shfl_xor(s, 2);
        s += __shfl_xor(s, 4); s += __shfl_xor(s, 8);
        if (lr == 0) sums4[((size_t)bh * QT_ + q0 + lg * 4 + r) * 4 + ns] = s;
    }
}

// -------------------- attn pass B: write attn + partial PV --------------------
// grid 2048 (XCD-swizzled): (bh, qt, ns of 4). wg = 64 q x 512 kv (8 tiles of 64).
// K staged (LDS dbuf, prefetch pipeline as R7). V = DIRECT register loads issued at tile
// start, consumed after QK+softmax (~250cy later) -> L2 latency hidden (T14 split).
// LDS = 16KB K dbuf + 8KB P = 24KB -> 6 wg/CU.
__global__ __launch_bounds__(256) void attn_pv(const u16* __restrict__ qh,
                                               const u16* __restrict__ kh,
                                               const u16* __restrict__ vt,
                                               const int* __restrict__ kv_mask,
                                               const float* __restrict__ sums4,
                                               float* __restrict__ attn_out,
                                               float* __restrict__ pvpart) {
    __shared__ __align__(16) u16 kbuf[2][64 * 64];
    __shared__ unsigned PW[4][16][32];  // per-wave packed bf16-pair P, granule-swizzled

    const int id = blockIdx.x;
    const int sw = (id & 7) * 256 + (id >> 3);  // XCD k gets 4 consecutive bh
    const int bh = sw >> 6, qt = (sw >> 2) & 15, ns = sw & 3;
    const int b = bh >> 3;
    const int tid = threadIdx.x, w = tid >> 6, lane = tid & 63;
    const int lr = lane & 15, lg = lane >> 4;
    const int q0 = qt * 64 + w * 16;

    const u16* qbase = qh + (bh * QT_ + q0) * DH_;
    const bf16x8 qf0 = ldbf8(qbase + lr * DH_ + lg * 8);   // Q pre-scaled by 0.125
    const bf16x8 qf1 = ldbf8(qbase + lr * DH_ + 32 + lg * 8);
    const u16* kbase = kh + (size_t)bh * (N_ * DH_) + ns * 512 * DH_;
    const u16* vbase = vt + (size_t)bh * (N_ * DH_) + ns * 512 * DH_;  // tiled [t][64d][64]
    const int* mbase = kv_mask + b * N_ + ns * 512;

    // total row sums -> inv
    float inv[4];
#pragma unroll
    for (int r = 0; r < 4; r++) {
        float4 s4 = *reinterpret_cast<const float4*>(
            sums4 + ((size_t)bh * QT_ + q0 + lg * 4 + r) * 4);
        float tot = s4.x + s4.y + s4.z + s4.w;
        inv[r] = (tot > 0.f) ? (1.0f / tot) : 0.f;  // all-masked row -> attn = ctx = 0
    }

    auto stage = [&](const u16* gsrc, u16* lbuf) {
#pragma unroll
        for (int i = 0; i < 2; i++) {
            const int r0 = w * 16 + i * 8;
            const int row = r0 + (lane >> 3);
            const u16* src = gsrc + row * 64 + (((lane & 7) ^ (row & 7)) * 8);
            g2lds16(src, lbuf + r0 * 64);
        }
    };

    f32x4 pv[4];
#pragma unroll
    for (int i = 0; i < 4; i++) pv[i] = f32x4{0.f, 0.f, 0.f, 0.f};
    unsigned(*P)[32] = PW[w];
    float* abase = attn_out + ((size_t)(bh * QT_ + q0)) * N_ + ns * 512;
    const int srow = lane >> 4, cq = lane & 15;  // store: 4 rows x 256B per instr

    stage(kbase, kbuf[0]);
    __syncthreads();
    for (int t = 0; t < 8; t++) {
        const u16* kc = kbuf[t & 1];
        if (t < 7) stage(kbase + (t + 1) * (64 * DH_), kbuf[(t + 1) & 1]);
        // V early-issue: 8 independent b128 loads (L2-resident), consumed after softmax
        bf16x8 vfr[8];
#pragma unroll
        for (int j = 0; j < 8; j++) {
            const int nb = j & 3, ks = j >> 2;
            vfr[j] = ldbf8(vbase + (t * 64 + nb * 16 + lr) * 64 + ks * 32 + lg * 8);
        }
#pragma unroll
        for (int n = 0; n < 4; n++) {
            const int krow = n * 16 + lr;
            const u16* kp = kc + krow * 64;
            bf16x8 k0 = ldbf8(kp + ((lg ^ (krow & 7)) * 8));
            bf16x8 k1 = ldbf8(kp + (((lg + 4) ^ (krow & 7)) * 8));
            f32x4 c = f32x4{0.f, 0.f, 0.f, 0.f};
            __builtin_amdgcn_s_setprio(1);
            c = MFMA16(qf0, k0, c);
            c = MFMA16(qf1, k1, c);
            __builtin_amdgcn_s_setprio(0);
            const bool keep = (mbase[t * 64 + n * 16 + lr] != 0);
#pragma unroll
            for (int r = 0; r < 4; r++) {
                float p = keep ? (__expf(c[r]) * inv[r]) : 0.f;  // normalized
                float hi = __shfl_xor(p, 1);
                __bf16 lo_b = (__bf16)p, hi_b = (__bf16)hi;
                unsigned pk = ((unsigned)__builtin_bit_cast(u16, hi_b) << 16) |
                              (unsigned)__builtin_bit_cast(u16, lo_b);
                if (!(lr & 1)) {
                    const int row = lg * 4 + r, c32 = n * 8 + (lr >> 1);
                    P[row][(((c32 >> 2) ^ (row & 7)) << 2) + (c32 & 3)] = pk;
                }
            }
        }
        // attn stores: read packed P (b64), unpack bf16->f32, 4 rows x 256B segments
#pragma unroll
        for (int i = 0; i < 4; i++) {
            const int row = i * 4 + srow, rw = row & 7;
            const int m = (((cq >> 1) ^ rw) << 2) + ((cq & 1) << 1);
            uint2 pp = *reinterpret_cast<const uint2*>(&P[row][m]);
            f32x4 vv;
            vv[0] = __builtin_bit_cast(float, pp.x << 16);
            vv[1] = __builtin_bit_cast(float, pp.x & 0xffff0000u);
            vv[2] = __builtin_bit_cast(float, pp.y << 16);
            vv[3] = __builtin_bit_cast(float, pp.y & 0xffff0000u);
            *reinterpret_cast<f32x4*>(abase + (size_t)row * N_ + t * 64 + cq * 4) = vv;
        }
        // PV: ctx[16q,64d] += P @ V-tile; A-frag = one swizzled b128 granule; V from regs
#pragma unroll
        for (int ks = 0; ks < 2; ks++) {
            const int g = (4 * ks + lg) ^ (lr & 7);
            uint4 a4 = *reinterpret_cast<const uint4*>(&P[lr][g << 2]);
            bf16x8 af = __builtin_bit_cast(bf16x8, a4);
            __builtin_amdgcn_s_setprio(1);
#pragma unroll
            for (int nb = 0; nb < 4; nb++)
                pv[nb] = MFMA16(af, vfr[ks * 4 + nb], pv[nb]);
            __builtin_amdgcn_s_setprio(0);
        }
        __syncthreads();
    }

    // partial ctx: pvpart[ns][bh][q][64]
    float* pbase = pvpart + (((size_t)ns * 32 + bh) * QT_) * DH_;
#pragma unroll
    for (int nb = 0; nb < 4; nb++)
#pragma unroll
        for (int r = 0; r < 4; r++)
            pbase[(size_t)(q0 + lg * 4 + r) * DH_ + nb * 16 + lr] = pv[nb][r];
}

// -------------------- ctx reduce: ctx[b,tok,h*64+d] = bf16(sum_ns pvpart) ------------
__global__ __launch_bounds__(256) void ctx_reduce(const float* __restrict__ pvpart,
                                                  u16* __restrict__ ctx) {
    const size_t SL = (size_t)32 * QT_ * DH_;  // slice stride (f32)
    const int i = blockIdx.x * 256 + threadIdx.x;  // 524288 threads, 4 elems each
    const int base = i * 4;
    const int d = base & 63, h = (base >> 6) & 7;
    const int bt = base >> 9;              // b*1024 + tok
    const size_t pi = (((size_t)(bt >> 10) * 8 + h) * QT_ + (bt & 1023)) * DH_ + d;
    f32x4 s0 = *reinterpret_cast<const f32x4*>(pvpart + pi);
    f32x4 s1 = *reinterpret_cast<const f32x4*>(pvpart + SL + pi);
    f32x4 s2 = *reinterpret_cast<const f32x4*>(pvpart + 2 * SL + pi);
    f32x4 s3 = *reinterpret_cast<const f32x4*>(pvpart + 3 * SL + pi);
    u16x4 o;
#pragma unroll
    for (int j = 0; j < 4; j++) o[j] = f2bf((s0[j] + s1[j]) + (s2[j] + s3[j]));
    *reinterpret_cast<u16x4*>(ctx + base) = o;
}

// -------------------- O projection: 64x64 tiles, grid 512 --------------------
__global__ __launch_bounds__(256) void proj_o(const u16* __restrict__ X,
                                              const u16* __restrict__ Wt,
                                              const float* __restrict__ bias,
                                              float* __restrict__ outp,
                                              const int* __restrict__ qmask) {
    __shared__ __align__(16) u16 la[2][64 * 64];
    __shared__ __align__(16) u16 lb[2][64 * 64];

    const int id = blockIdx.x;             // 512 blocks
    const int sw = (id & 7) * 64 + (id >> 3);
    const int m0 = (sw >> 3) * 64, n0 = (sw & 7) * 64;

    const int tid = threadIdx.x, w = tid >> 6, lane = tid & 63;
    const int lr = lane & 15, lg = lane >> 4;
    const int wml = (w >> 1) * 32, wnl = (w & 1) * 32;

    auto stage = [&](const u16* gsrc, u16* lbuf) {
#pragma unroll
        for (int i = 0; i < 2; i++) {
            const int r0 = w * 16 + i * 8;
            const int row = r0 + (lane >> 3);
            const u16* src = gsrc + row * E_ + (((lane & 7) ^ (row & 7)) * 8);
            g2lds16(src, lbuf + r0 * 64);
        }
    };

    f32x4 acc[2][2];
#pragma unroll
    for (int i = 0; i < 2; i++)
#pragma unroll
        for (int j = 0; j < 2; j++) acc[i][j] = f32x4{0.f, 0.f, 0.f, 0.f};

    stage(X + m0 * E_, la[0]);
    stage(Wt + n0 * E_, lb[0]);
    __syncthreads();
    int buf = 0;
    for (int kt = 0; kt < E_ / 64; kt++) {
        if (kt + 1 < E_ / 64) {
            stage(X + m0 * E_ + (kt + 1) * 64, la[buf ^ 1]);
            stage(Wt + n0 * E_ + (kt + 1) * 64, lb[buf ^ 1]);
        }
#pragma unroll
        for (int ks = 0; ks < 2; ks++) {
            bf16x8 a[2], bb[2];
#pragma unroll
            for (int mb = 0; mb < 2; mb++) {
                const int r = wml + mb * 16 + lr;
                a[mb] = ldbf8(la[buf] + r * 64 + (((ks * 4 + lg) ^ (r & 7)) * 8));
            }
#pragma unroll
            for (int nb = 0; nb < 2; nb++) {
                const int r = wnl + nb * 16 + lr;
                bb[nb] = ldbf8(lb[buf] + r * 64 + (((ks * 4 + lg) ^ (r & 7)) * 8));
            }
            __builtin_amdgcn_s_setprio(1);
#pragma unroll
            for (int mb = 0; mb < 2; mb++)
#pragma unroll
                for (int nb = 0; nb < 2; nb++)
                    acc[mb][nb] = MFMA16(a[mb], bb[nb], acc[mb][nb]);
            __builtin_amdgcn_s_setprio(0);
        }
        __syncthreads();
        buf ^= 1;
    }

#pragma unroll
    for (int mb = 0; mb < 2; mb++) {
#pragma unroll
        for (int nb = 0; nb < 2; nb++) {
            const int col = n0 + wnl + nb * 16 + lr;
            const float bs = bias[col];
#pragma unroll
            for (int r = 0; r < 4; r++) {
                const int row = m0 + wml + mb * 16 + lg * 4 + r;
                float v = acc[mb][nb][r] + bs;
                float m = (qmask[row] != 0) ? 1.0f : 0.0f;
                outp[row * E_ + col] = v * m;
            }
        }
    }
}

// -------------------- host launch --------------------
extern "C" void kernel_launch(void* const* d_in, const int* in_sizes, int n_in,
                              void* d_out, int out_size, void* d_ws, size_t ws_size,
                              hipStream_t stream) {
    (void)in_sizes; (void)n_in; (void)out_size; (void)ws_size;
    const float* q   = (const float*)d_in[0];
    const float* kv  = (const float*)d_in[1];
    const int* q_mask  = (const int*)d_in[2];
    const int* kv_mask = (const int*)d_in[3];
    const int* q_pos   = (const int*)d_in[4];
    const int* kv_pos  = (const int*)d_in[5];
    const float* Wq = (const float*)d_in[6];  const float* bq = (const float*)d_in[7];
    const float* Wk = (const float*)d_in[8];  const float* bk = (const float*)d_in[9];
    const float* Wv = (const float*)d_in[10]; const float* bv = (const float*)d_in[11];
    const float* Wo = (const float*)d_in[12]; const float* bo = (const float*)d_in[13];
    float* outp = (float*)d_out;

    char* ws = (char*)d_ws;
    size_t off = 0;
    auto carve = [&](size_t bytes) -> void* {
        void* p = ws + off;
        off = (off + bytes + 255) & ~(size_t)255;
        return p;
    };
    u16* qbf    = (u16*)carve((size_t)B_ * QT_ * E_ * 2);
    u16* kvbf   = (u16*)carve((size_t)B_ * N_ * E_ * 2);
    u16* wt4    = (u16*)carve((size_t)4 * E_ * E_ * 2);  // [Wq^T|Wk^T|Wv^T|Wo^T]
    u16* qhh    = (u16*)carve((size_t)B_ * H_ * QT_ * DH_ * 2);
    u16* khh    = (u16*)carve((size_t)B_ * H_ * N_ * DH_ * 2);
    u16* vt     = (u16*)carve((size_t)B_ * H_ * DH_ * N_ * 2);  // tiled [bh][32][64][64]
    u16* ctx    = (u16*)carve((size_t)B_ * QT_ * E_ * 2);
    float2* tq  = (float2*)carve((size_t)B_ * QT_ * 16 * sizeof(float2));
    float2* tk  = (float2*)carve((size_t)B_ * N_ * 16 * sizeof(float2));
    float* sums4  = (float*)carve((size_t)B_ * H_ * QT_ * 4 * sizeof(float));
    float* pvpart = (float*)carve((size_t)4 * B_ * H_ * QT_ * DH_ * sizeof(float));

    cvt_all<<<6144, 256, 0, stream>>>(q, kv, qbf, kvbf);
    wt_all<<<dim3(8, 8, 4), 256, 0, stream>>>(Wq, Wk, Wv, Wo, wt4);
    rope_all<<<768, 256, 0, stream>>>(q_pos, kv_pos, tq, tk);

    proj_qkv<<<640, 256, 0, stream>>>(qbf, kvbf, wt4, bq, bk, bv, qhh, khh, vt, tq, tk);

    attn_sums<<<2048, 256, 0, stream>>>(qhh, khh, kv_mask, sums4);
    attn_pv<<<2048, 256, 0, stream>>>(qhh, khh, vt, kv_mask, sums4,
                                      outp + (size_t)B_ * QT_ * E_, pvpart);
    ctx_reduce<<<2048, 256, 0, stream>>>(pvpart, ctx);

    proj_o<<<512, 256, 0, stream>>>(ctx, wt4 + 3 * 512 * 512, bo, outp, q_mask);
}

// Round 10
// 162.415 us; speedup vs baseline: 1.7276x; 1.3305x over previous
//
#include <hip/hip_runtime.h>
#include <hip/hip_bf16.h>

// Problem constants (CrossEncoder): B=4, QT=1024, N=2048, E=512, H=8, Dh=64
#define B_  4
#define QT_ 1024
#define N_  2048
#define E_  512
#define H_  8
#define DH_ 64

typedef float  f32x4  __attribute__((ext_vector_type(4)));
typedef __bf16 bf16x8 __attribute__((ext_vector_type(8)));
typedef unsigned short u16;
typedef u16 u16x4 __attribute__((ext_vector_type(4)));

// round-to-nearest-even f32 -> bf16
static __device__ __forceinline__ u16 f2bf(float f) {
    unsigned u = __builtin_bit_cast(unsigned, f);
    return (u16)((u + 0x7fffu + ((u >> 16) & 1u)) >> 16);
}

static __device__ __forceinline__ bf16x8 ldbf8(const u16* p) {
    uint4 v = *reinterpret_cast<const uint4*>(p);
    return __builtin_bit_cast(bf16x8, v);
}

#define MFMA16(a, b, c) __builtin_amdgcn_mfma_f32_16x16x32_bf16((a), (b), (c), 0, 0, 0)

// async global->LDS, 16B per lane; LDS dest = uniform base + lane*16 (linear)
static __device__ __forceinline__ void g2lds16(const u16* g, u16* l) {
    __builtin_amdgcn_global_load_lds((__attribute__((address_space(1))) void*)(void*)g,
                                     (__attribute__((address_space(3))) void*)l, 16, 0, 0);
}

// -------------------- fused f32 -> bf16 convert (q + kv) --------------------
__global__ __launch_bounds__(256) void cvt_all(const float* __restrict__ q,
                                               const float* __restrict__ kv,
                                               u16* __restrict__ qbf,
                                               u16* __restrict__ kvbf) {
    const int QN4 = B_ * QT_ * E_ / 4;  // 524288
    int i = blockIdx.x * 256 + threadIdx.x;
    const float4* s;
    ushort4* d;
    if (i < QN4) {
        s = reinterpret_cast<const float4*>(q) + i;
        d = reinterpret_cast<ushort4*>(qbf) + i;
    } else {
        int j = i - QN4;
        s = reinterpret_cast<const float4*>(kv) + j;
        d = reinterpret_cast<ushort4*>(kvbf) + j;
    }
    float4 v = *s;
    ushort4 o;
    o.x = f2bf(v.x); o.y = f2bf(v.y); o.z = f2bf(v.z); o.w = f2bf(v.w);
    *d = o;
}

// -------------------- batched weight transpose: wt4[z][n][k] = bf16(Wz[k][n]) ------------
__global__ __launch_bounds__(256) void wt_all(const float* __restrict__ Wq,
                                              const float* __restrict__ Wk,
                                              const float* __restrict__ Wv,
                                              const float* __restrict__ Wo,
                                              u16* __restrict__ wt4) {
    __shared__ float t[64][65];
    const float* W = (blockIdx.z == 0) ? Wq : (blockIdx.z == 1) ? Wk : (blockIdx.z == 2) ? Wv : Wo;
    u16* dst = wt4 + (size_t)blockIdx.z * E_ * E_;
    int k0 = blockIdx.x * 64, n0 = blockIdx.y * 64;
    int tid = threadIdx.x;
#pragma unroll
    for (int i = 0; i < 16; i++) {
        int idx = tid + i * 256, r = idx >> 6, c = idx & 63;
        t[r][c] = W[(k0 + r) * E_ + n0 + c];
    }
    __syncthreads();
#pragma unroll
    for (int i = 0; i < 16; i++) {
        int idx = tid + i * 256, r = idx >> 6, c = idx & 63;
        dst[(n0 + r) * E_ + k0 + c] = f2bf(t[c][r]);
    }
}

// -------------------- fused RoPE tables (reference quirk: freq index = d>>2) ----------
__global__ __launch_bounds__(256) void rope_all(const int* __restrict__ qpos,
                                                const int* __restrict__ kvpos,
                                                float2* __restrict__ tq,
                                                float2* __restrict__ tk) {
    const int QROWS = B_ * QT_;  // 4096
    int i = blockIdx.x * 256 + threadIdx.x;  // 196608 total
    int k = i & 15, row = i >> 4;
    float fr = exp2f((float)k * -0.41524101186092028f);  // log2(10000)/32
    int p;
    float2* dst;
    if (row < QROWS) { p = qpos[row]; dst = tq + i; }
    else { p = kvpos[row - QROWS]; dst = tk + (i - QROWS * 16); }
    float sn, cs;
    sincosf((float)p * fr, &sn, &cs);
    *dst = make_float2(cs, sn);
}

// -------------------- fused Q+K+V projection GEMM (BK=32: 32KB LDS, all 640 resident) ----
// 640 blocks: 128 Q-role (M=4096,N=512) + 512 KV-role (M=8192,N=1024 fused K|V).
// Q epilogue: RoPE * 0.125 -> qhh [B,H,QT,64]; K: RoPE -> khh; V: tiled vt [bh][n/64][d][64]
__global__ __launch_bounds__(256) void proj_qkv(const u16* __restrict__ qbf,
                                                const u16* __restrict__ kvbf,
                                                const u16* __restrict__ wt4,
                                                const float* __restrict__ bq,
                                                const float* __restrict__ bk,
                                                const float* __restrict__ bv,
                                                u16* __restrict__ qhh,
                                                u16* __restrict__ khh,
                                                u16* __restrict__ vt,
                                                const float2* __restrict__ tq,
                                                const float2* __restrict__ tk) {
    __shared__ __align__(16) u16 la[2][128 * 32];
    __shared__ __align__(16) u16 lb[2][128 * 32];

    const int id = blockIdx.x;
    const int sw = (id & 7) * 80 + (id >> 3);  // bijective XCD swizzle over 640
    const bool isQ = (sw < 128);
    int m0, n0;
    const u16 *X, *W;
    if (isQ) { m0 = (sw >> 2) * 128; n0 = (sw & 3) * 128; X = qbf; W = wt4; }
    else { const int s2 = sw - 128; m0 = (s2 >> 3) * 128; n0 = (s2 & 7) * 128; X = kvbf; W = wt4 + 512 * 512; }

    const int tid = threadIdx.x, w = tid >> 6, lane = tid & 63;
    const int lr = lane & 15, lg = lane >> 4;
    const int wml = (w >> 1) * 64, wnl = (w & 1) * 64;

    auto stage = [&](const u16* gsrc, u16* lbuf) {
#pragma unroll
        for (int i = 0; i < 2; i++) {
            const int r0 = w * 32 + i * 16;
            const int row = r0 + (lane >> 2);
            const u16* src = gsrc + row * E_ + (((lane & 3) ^ (row & 3)) * 8);
            g2lds16(src, lbuf + r0 * 32);
        }
    };

    f32x4 acc[4][4];
#pragma unroll
    for (int i = 0; i < 4; i++)
#pragma unroll
        for (int j = 0; j < 4; j++) acc[i][j] = f32x4{0.f, 0.f, 0.f, 0.f};

    stage(X + m0 * E_, la[0]);
    stage(W + n0 * E_, lb[0]);
    __syncthreads();
    int buf = 0;
    for (int kt = 0; kt < E_ / 32; kt++) {
        if (kt + 1 < E_ / 32) {
            stage(X + m0 * E_ + (kt + 1) * 32, la[buf ^ 1]);
            stage(W + n0 * E_ + (kt + 1) * 32, lb[buf ^ 1]);
        }
        bf16x8 a[4], bb[4];
#pragma unroll
        for (int mb = 0; mb < 4; mb++) {
            const int r = wml + mb * 16 + lr;
            a[mb] = ldbf8(la[buf] + r * 32 + ((lg ^ (r & 3)) * 8));
        }
#pragma unroll
        for (int nb = 0; nb < 4; nb++) {
            const int r = wnl + nb * 16 + lr;
            bb[nb] = ldbf8(lb[buf] + r * 32 + ((lg ^ (r & 3)) * 8));
        }
        __builtin_amdgcn_s_setprio(1);
#pragma unroll
        for (int mb = 0; mb < 4; mb++)
#pragma unroll
            for (int nb = 0; nb < 4; nb++)
                acc[mb][nb] = MFMA16(a[mb], bb[nb], acc[mb][nb]);
        __builtin_amdgcn_s_setprio(0);
        __syncthreads();
        buf ^= 1;
    }

    const bool isV = !isQ && (n0 >= 512);  // wg-uniform
#pragma unroll
    for (int mb = 0; mb < 4; mb++) {
#pragma unroll
        for (int nb = 0; nb < 4; nb++) {
            const int col = n0 + wnl + nb * 16 + lr;  // C col = lane&15
            const float bs = isQ ? bq[col] : (isV ? bv[col - 512] : bk[col]);
#pragma unroll
            for (int r = 0; r < 4; r++) {
                const int row = m0 + wml + mb * 16 + lg * 4 + r;  // C row = (lane>>4)*4+reg
                float v = acc[mb][nb][r] + bs;
                if (isV) {
                    const int cv = col - 512, d = cv & 63, h = cv >> 6;
                    const int b = row >> 11, n = row & 2047;
                    vt[(((b * H_ + h) * (N_ / 64) + (n >> 6)) * DH_ + d) * 64 + (n & 63)] = f2bf(v);
                } else {
                    const int d = col & 63, h = col >> 6;
                    float2 t = isQ ? tq[row * 16 + (d >> 2)] : tk[row * 16 + (d >> 2)];
                    float other = __shfl_xor(v, 1);  // pair mate: col^1 lives in lane^1
                    float y = (d & 1) ? (other * t.y + v * t.x) : (v * t.x - other * t.y);
                    if (isQ) {
                        y *= 0.125f;  // softmax scale folded into Q
                        const int b = row >> 10, tok = row & 1023;
                        qhh[((b * H_ + h) * QT_ + tok) * DH_ + d] = f2bf(y);
                    } else {
                        const int b = row >> 11, tok = row & 2047;
                        khh[((b * H_ + h) * N_ + tok) * DH_ + d] = f2bf(y);
                    }
                }
            }
        }
    }
}

// -------------------- attn pass A: partial row sums of exp(score) (staged, proven) ------
// grid 2048 (XCD-swizzled): (bh, qt, ns). wg = 64 q (4 waves x 16) x 512 kv (8 tiles).
// K staged via global_load_lds (dbuf 16KB) - prefetch pipeline. Writes sums4[..*4+ns].
__global__ __launch_bounds__(256) void attn_sums(const u16* __restrict__ qh,
                                                 const u16* __restrict__ kh,
                                                 const int* __restrict__ kv_mask,
                                                 float* __restrict__ sums4) {
    __shared__ __align__(16) u16 kbuf[2][64 * 64];

    const int id = blockIdx.x;
    const int sw = (id & 7) * 256 + (id >> 3);  // XCD k gets 4 consecutive bh
    const int bh = sw >> 6, qt = (sw >> 2) & 15, ns = sw & 3;
    const int b = bh >> 3;
    const int tid = threadIdx.x, w = tid >> 6, lane = tid & 63;
    const int lr = lane & 15, lg = lane >> 4;
    const int q0 = qt * 64 + w * 16;

    const u16* qbase = qh + (bh * QT_ + q0) * DH_;
    const bf16x8 qf0 = ldbf8(qbase + lr * DH_ + lg * 8);   // Q pre-scaled by 0.125
    const bf16x8 qf1 = ldbf8(qbase + lr * DH_ + 32 + lg * 8);
    const u16* kbase = kh + (size_t)bh * (N_ * DH_) + ns * 512 * DH_;
    const int* mbase = kv_mask + b * N_ + ns * 512;

    auto stage = [&](const u16* gsrc, u16* lbuf) {
#pragma unroll
        for (int i = 0; i < 2; i++) {
            const int r0 = w * 16 + i * 8;
            const int row = r0 + (lane >> 3);
            const u16* src = gsrc + row * 64 + (((lane & 7) ^ (row & 7)) * 8);
            g2lds16(src, lbuf + r0 * 64);
        }
    };

    float lsum[4] = {0.f, 0.f, 0.f, 0.f};
    stage(kbase, kbuf[0]);
    __syncthreads();
    for (int t = 0; t < 8; t++) {
        const u16* kc = kbuf[t & 1];
        if (t < 7) stage(kbase + (t + 1) * (64 * DH_), kbuf[(t + 1) & 1]);
#pragma unroll
        for (int n = 0; n < 4; n++) {
            const int krow = n * 16 + lr;
            const u16* kp = kc + krow * 64;
            bf16x8 k0 = ldbf8(kp + ((lg ^ (krow & 7)) * 8));
            bf16x8 k1 = ldbf8(kp + (((lg + 4) ^ (krow & 7)) * 8));
            f32x4 c = f32x4{0.f, 0.f, 0.f, 0.f};
            __builtin_amdgcn_s_setprio(1);
            c = MFMA16(qf0, k0, c);
            c = MFMA16(qf1, k1, c);
            __builtin_amdgcn_s_setprio(0);
            const bool keep = (mbase[t * 64 + n * 16 + lr] != 0);
#pragma unroll
            for (int r = 0; r < 4; r++) lsum[r] += keep ? __expf(c[r]) : 0.f;
        }
        __syncthreads();
    }
#pragma unroll
    for (int r = 0; r < 4; r++) {
        float s = lsum[r];
        s += __shfl_xor(s, 1); s += __shfl_xor(s, 2);
        s += __shfl_xor(s, 4); s += __shfl_xor(s, 8);
        if (lr == 0) sums4[((size_t)bh * QT_ + q0 + lg * 4 + r) * 4 + ns] = s;
    }
}

// -------------------- attn pass B: write attn + partial PV (KVBLK=32) --------------------
// grid 2048 (XCD-swizzled): (bh, qt, ns of 4). wg = 64 q x 512 kv (16 tiles of 32).
// R7-proven staged template, tiles halved: LDS = 8K Kdbuf + 8K Vdbuf + 5.25K P = 21.5KB
// -> 7 wg/CU resident (vs 4 at KVBLK=64). Same sync structure (stage t+1 || compute t).
__global__ __launch_bounds__(256) void attn_pv(const u16* __restrict__ qh,
                                               const u16* __restrict__ kh,
                                               const u16* __restrict__ vt,
                                               const int* __restrict__ kv_mask,
                                               const float* __restrict__ sums4,
                                               float* __restrict__ attn_out,
                                               float* __restrict__ pvpart) {
    __shared__ __align__(16) u16 kbuf[2][32 * 64];  // K tile [32 kv][64 d]
    __shared__ __align__(16) u16 vbuf[2][64 * 32];  // V tile [64 d][32 kv]
    __shared__ __align__(16) unsigned PW[4][16][20]; // packed bf16-pair P, row pad 20 (2-way)

    const int id = blockIdx.x;
    const int sw = (id & 7) * 256 + (id >> 3);  // XCD k gets 4 consecutive bh
    const int bh = sw >> 6, qt = (sw >> 2) & 15, ns = sw & 3;
    const int b = bh >> 3;
    const int tid = threadIdx.x, w = tid >> 6, lane = tid & 63;
    const int lr = lane & 15, lg = lane >> 4;
    const int q0 = qt * 64 + w * 16;

    const u16* qbase = qh + (bh * QT_ + q0) * DH_;
    const bf16x8 qf0 = ldbf8(qbase + lr * DH_ + lg * 8);   // Q pre-scaled by 0.125
    const bf16x8 qf1 = ldbf8(qbase + lr * DH_ + 32 + lg * 8);
    const u16* kbase = kh + (size_t)bh * (N_ * DH_) + ns * 512 * DH_;
    const u16* vbase = vt + (size_t)bh * (N_ * DH_) + ns * 512 * DH_;  // [8 t64][64 d][64]
    const int* mbase = kv_mask + b * N_ + ns * 512;

    // total row sums -> inv
    float inv[4];
#pragma unroll
    for (int r = 0; r < 4; r++) {
        float4 s4 = *reinterpret_cast<const float4*>(
            sums4 + ((size_t)bh * QT_ + q0 + lg * 4 + r) * 4);
        float tot = s4.x + s4.y + s4.z + s4.w;
        inv[r] = (tot > 0.f) ? (1.0f / tot) : 0.f;  // all-masked row -> attn = ctx = 0
    }

    // K stage: 32 rows x 64 d = 4KB; per wave 8 rows = 1 instr. src pre-swizzled ^(row&7)
    auto stageK = [&](int t, u16* lbuf) {
        const int r0 = w * 8;
        const int row = r0 + (lane >> 3);
        const u16* src = kbase + (t * 32 + row) * 64 + (((lane & 7) ^ (row & 7)) * 8);
        g2lds16(src, lbuf + r0 * 64);
    };
    // V stage: 64 d x 32 kv = 4KB; per wave 16 d-rows = 1 instr. granule ^((d>>1)&3)
    // (row stride 64B = 16 banks, so XOR on (d>>1) keeps read aliasing at 2-way = free)
    auto stageV = [&](int t, u16* lbuf) {
        const int r0 = w * 16;
        const int row = r0 + (lane >> 2);        // d index
        const u16* src = vbase + (((t >> 1) * 64 + row) * 64) + ((t & 1) * 32) +
                         (((lane & 3) ^ ((row >> 1) & 3)) * 8);
        g2lds16(src, lbuf + r0 * 32);
    };

    f32x4 pv[4];
#pragma unroll
    for (int i = 0; i < 4; i++) pv[i] = f32x4{0.f, 0.f, 0.f, 0.f};
    unsigned(*P)[20] = PW[w];
    float* abase = attn_out + ((size_t)(bh * QT_ + q0)) * N_ + ns * 512;

    stageK(0, kbuf[0]);
    stageV(0, vbuf[0]);
    __syncthreads();
    for (int t = 0; t < 16; t++) {
        const u16* kc = kbuf[t & 1];
        const u16* vc = vbuf[t & 1];
        if (t < 15) {
            stageK(t + 1, kbuf[(t + 1) & 1]);
            stageV(t + 1, vbuf[(t + 1) & 1]);
        }
#pragma unroll
        for (int n = 0; n < 2; n++) {
            const int krow = n * 16 + lr;
            const u16* kp = kc + krow * 64;
            bf16x8 k0 = ldbf8(kp + ((lg ^ (krow & 7)) * 8));
            bf16x8 k1 = ldbf8(kp + (((lg + 4) ^ (krow & 7)) * 8));
            f32x4 c = f32x4{0.f, 0.f, 0.f, 0.f};
            __builtin_amdgcn_s_setprio(1);
            c = MFMA16(qf0, k0, c);
            c = MFMA16(qf1, k1, c);
            __builtin_amdgcn_s_setprio(0);
            const bool keep = (mbase[t * 32 + krow] != 0);
#pragma unroll
            for (int r = 0; r < 4; r++) {
                float p = keep ? (__expf(c[r]) * inv[r]) : 0.f;  // normalized
                float hi = __shfl_xor(p, 1);
                __bf16 lo_b = (__bf16)p, hi_b = (__bf16)hi;
                unsigned pk = ((unsigned)__builtin_bit_cast(u16, hi_b) << 16) |
                              (unsigned)__builtin_bit_cast(u16, lo_b);
                if (!(lr & 1)) {
                    const int row = lg * 4 + r, c32 = n * 8 + (lr >> 1);
                    P[row][(((c32 >> 2) ^ (row & 3)) << 2) + (c32 & 3)] = pk;
                }
            }
        }
        // attn stores: b64 P read + unpack; each instr = 8 rows x 128B contiguous
#pragma unroll
        for (int i = 0; i < 2; i++) {
            const int row = i * 8 + (lane >> 3), cq = lane & 7;
            const int m = (((cq >> 1) ^ (row & 3)) << 2) + ((cq & 1) << 1);
            uint2 pp = *reinterpret_cast<const uint2*>(&P[row][m]);
            f32x4 vv;
            vv[0] = __builtin_bit_cast(float, pp.x << 16);
            vv[1] = __builtin_bit_cast(float, pp.x & 0xffff0000u);
            vv[2] = __builtin_bit_cast(float, pp.y << 16);
            vv[3] = __builtin_bit_cast(float, pp.y & 0xffff0000u);
            *reinterpret_cast<f32x4*>(abase + (size_t)row * N_ + t * 32 + cq * 4) = vv;
        }
        // PV: ctx[16q,64d] += P @ V-tile (K=32, one MFMA step x 4 nb)
        {
            uint4 a4 = *reinterpret_cast<const uint4*>(&P[lr][(lg ^ (lr & 3)) << 2]);
            bf16x8 af = __builtin_bit_cast(bf16x8, a4);
            __builtin_amdgcn_s_setprio(1);
#pragma unroll
            for (int nb = 0; nb < 4; nb++) {
                const int vrow = nb * 16 + lr;
                bf16x8 bv = ldbf8(vc + vrow * 32 + ((lg ^ ((vrow >> 1) & 3)) * 8));
                pv[nb] = MFMA16(af, bv, pv[nb]);
            }
            __builtin_amdgcn_s_setprio(0);
        }
        __syncthreads();
    }

    // partial ctx: pvpart[ns][bh][q][64]
    float* pbase = pvpart + (((size_t)ns * 32 + bh) * QT_) * DH_;
#pragma unroll
    for (int nb = 0; nb < 4; nb++)
#pragma unroll
        for (int r = 0; r < 4; r++)
            pbase[(size_t)(q0 + lg * 4 + r) * DH_ + nb * 16 + lr] = pv[nb][r];
}

// -------------------- ctx reduce: ctx[b,tok,h*64+d] = bf16(sum_ns pvpart) ------------
__global__ __launch_bounds__(256) void ctx_reduce(const float* __restrict__ pvpart,
                                                  u16* __restrict__ ctx) {
    const size_t SL = (size_t)32 * QT_ * DH_;  // slice stride (f32)
    const int i = blockIdx.x * 256 + threadIdx.x;  // 524288 threads, 4 elems each
    const int base = i * 4;
    const int d = base & 63, h = (base >> 6) & 7;
    const int bt = base >> 9;              // b*1024 + tok
    const size_t pi = (((size_t)(bt >> 10) * 8 + h) * QT_ + (bt & 1023)) * DH_ + d;
    f32x4 s0 = *reinterpret_cast<const f32x4*>(pvpart + pi);
    f32x4 s1 = *reinterpret_cast<const f32x4*>(pvpart + SL + pi);
    f32x4 s2 = *reinterpret_cast<const f32x4*>(pvpart + 2 * SL + pi);
    f32x4 s3 = *reinterpret_cast<const f32x4*>(pvpart + 3 * SL + pi);
    u16x4 o;
#pragma unroll
    for (int j = 0; j < 4; j++) o[j] = f2bf((s0[j] + s1[j]) + (s2[j] + s3[j]));
    *reinterpret_cast<u16x4*>(ctx + base) = o;
}

// -------------------- O projection: 64x64 tiles, grid 512 --------------------
__global__ __launch_bounds__(256) void proj_o(const u16* __restrict__ X,
                                              const u16* __restrict__ Wt,
                                              const float* __restrict__ bias,
                                              float* __restrict__ outp,
                                              const int* __restrict__ qmask) {
    __shared__ __align__(16) u16 la[2][64 * 64];
    __shared__ __align__(16) u16 lb[2][64 * 64];

    const int id = blockIdx.x;             // 512 blocks
    const int sw = (id & 7) * 64 + (id >> 3);
    const int m0 = (sw >> 3) * 64, n0 = (sw & 7) * 64;

    const int tid = threadIdx.x, w = tid >> 6, lane = tid & 63;
    const int lr = lane & 15, lg = lane >> 4;
    const int wml = (w >> 1) * 32, wnl = (w & 1) * 32;

    auto stage = [&](const u16* gsrc, u16* lbuf) {
#pragma unroll
        for (int i = 0; i < 2; i++) {
            const int r0 = w * 16 + i * 8;
            const int row = r0 + (lane >> 3);
            const u16* src = gsrc + row * E_ + (((lane & 7) ^ (row & 7)) * 8);
            g2lds16(src, lbuf + r0 * 64);
        }
    };

    f32x4 acc[2][2];
#pragma unroll
    for (int i = 0; i < 2; i++)
#pragma unroll
        for (int j = 0; j < 2; j++) acc[i][j] = f32x4{0.f, 0.f, 0.f, 0.f};

    stage(X + m0 * E_, la[0]);
    stage(Wt + n0 * E_, lb[0]);
    __syncthreads();
    int buf = 0;
    for (int kt = 0; kt < E_ / 64; kt++) {
        if (kt + 1 < E_ / 64) {
            stage(X + m0 * E_ + (kt + 1) * 64, la[buf ^ 1]);
            stage(Wt + n0 * E_ + (kt + 1) * 64, lb[buf ^ 1]);
        }
#pragma unroll
        for (int ks = 0; ks < 2; ks++) {
            bf16x8 a[2], bb[2];
#pragma unroll
            for (int mb = 0; mb < 2; mb++) {
                const int r = wml + mb * 16 + lr;
                a[mb] = ldbf8(la[buf] + r * 64 + (((ks * 4 + lg) ^ (r & 7)) * 8));
            }
#pragma unroll
            for (int nb = 0; nb < 2; nb++) {
                const int r = wnl + nb * 16 + lr;
                bb[nb] = ldbf8(lb[buf] + r * 64 + (((ks * 4 + lg) ^ (r & 7)) * 8));
            }
            __builtin_amdgcn_s_setprio(1);
#pragma unroll
            for (int mb = 0; mb < 2; mb++)
#pragma unroll
                for (int nb = 0; nb < 2; nb++)
                    acc[mb][nb] = MFMA16(a[mb], bb[nb], acc[mb][nb]);
            __builtin_amdgcn_s_setprio(0);
        }
        __syncthreads();
        buf ^= 1;
    }

#pragma unroll
    for (int mb = 0; mb < 2; mb++) {
#pragma unroll
        for (int nb = 0; nb < 2; nb++) {
            const int col = n0 + wnl + nb * 16 + lr;
            const float bs = bias[col];
#pragma unroll
            for (int r = 0; r < 4; r++) {
                const int row = m0 + wml + mb * 16 + lg * 4 + r;
                float v = acc[mb][nb][r] + bs;
                float m = (qmask[row] != 0) ? 1.0f : 0.0f;
                outp[row * E_ + col] = v * m;
            }
        }
    }
}

// -------------------- host launch --------------------
extern "C" void kernel_launch(void* const* d_in, const int* in_sizes, int n_in,
                              void* d_out, int out_size, void* d_ws, size_t ws_size,
                              hipStream_t stream) {
    (void)in_sizes; (void)n_in; (void)out_size; (void)ws_size;
    const float* q   = (const float*)d_in[0];
    const float* kv  = (const float*)d_in[1];
    const int* q_mask  = (const int*)d_in[2];
    const int* kv_mask = (const int*)d_in[3];
    const int* q_pos   = (const int*)d_in[4];
    const int* kv_pos  = (const int*)d_in[5];
    const float* Wq = (const float*)d_in[6];  const float* bq = (const float*)d_in[7];
    const float* Wk = (const float*)d_in[8];  const float* bk = (const float*)d_in[9];
    const float* Wv = (const float*)d_in[10]; const float* bv = (const float*)d_in[11];
    const float* Wo = (const float*)d_in[12]; const float* bo = (const float*)d_in[13];
    float* outp = (float*)d_out;

    char* ws = (char*)d_ws;
    size_t off = 0;
    auto carve = [&](size_t bytes) -> void* {
        void* p = ws + off;
        off = (off + bytes + 255) & ~(size_t)255;
        return p;
    };
    u16* qbf    = (u16*)carve((size_t)B_ * QT_ * E_ * 2);
    u16* kvbf   = (u16*)carve((size_t)B_ * N_ * E_ * 2);
    u16* wt4    = (u16*)carve((size_t)4 * E_ * E_ * 2);  // [Wq^T|Wk^T|Wv^T|Wo^T]
    u16* qhh    = (u16*)carve((size_t)B_ * H_ * QT_ * DH_ * 2);
    u16* khh    = (u16*)carve((size_t)B_ * H_ * N_ * DH_ * 2);
    u16* vt     = (u16*)carve((size_t)B_ * H_ * DH_ * N_ * 2);  // tiled [bh][32][64][64]
    u16* ctx    = (u16*)carve((size_t)B_ * QT_ * E_ * 2);
    float2* tq  = (float2*)carve((size_t)B_ * QT_ * 16 * sizeof(float2));
    float2* tk  = (float2*)carve((size_t)B_ * N_ * 16 * sizeof(float2));
    float* sums4  = (float*)carve((size_t)B_ * H_ * QT_ * 4 * sizeof(float));
    float* pvpart = (float*)carve((size_t)4 * B_ * H_ * QT_ * DH_ * sizeof(float));

    cvt_all<<<6144, 256, 0, stream>>>(q, kv, qbf, kvbf);
    wt_all<<<dim3(8, 8, 4), 256, 0, stream>>>(Wq, Wk, Wv, Wo, wt4);
    rope_all<<<768, 256, 0, stream>>>(q_pos, kv_pos, tq, tk);

    proj_qkv<<<640, 256, 0, stream>>>(qbf, kvbf, wt4, bq, bk, bv, qhh, khh, vt, tq, tk);

    attn_sums<<<2048, 256, 0, stream>>>(qhh, khh, kv_mask, sums4);
    attn_pv<<<2048, 256, 0, stream>>>(qhh, khh, vt, kv_mask, sums4,
                                      outp + (size_t)B_ * QT_ * E_, pvpart);
    ctx_reduce<<<2048, 256, 0, stream>>>(pvpart, ctx);

    proj_o<<<512, 256, 0, stream>>>(ctx, wt4 + 3 * 512 * 512, bo, outp, q_mask);
}

// Round 11
// 158.961 us; speedup vs baseline: 1.7651x; 1.0217x over previous
//
#include <hip/hip_runtime.h>
#include <hip/hip_bf16.h>

// Problem constants (CrossEncoder): B=4, QT=1024, N=2048, E=512, H=8, Dh=64
#define B_  4
#define QT_ 1024
#define N_  2048
#define E_  512
#define H_  8
#define DH_ 64

typedef float  f32x4  __attribute__((ext_vector_type(4)));
typedef __bf16 bf16x8 __attribute__((ext_vector_type(8)));
typedef unsigned short u16;
typedef u16 u16x4 __attribute__((ext_vector_type(4)));

// round-to-nearest-even f32 -> bf16
static __device__ __forceinline__ u16 f2bf(float f) {
    unsigned u = __builtin_bit_cast(unsigned, f);
    return (u16)((u + 0x7fffu + ((u >> 16) & 1u)) >> 16);
}

static __device__ __forceinline__ bf16x8 ldbf8(const u16* p) {
    uint4 v = *reinterpret_cast<const uint4*>(p);
    return __builtin_bit_cast(bf16x8, v);
}

#define MFMA16(a, b, c) __builtin_amdgcn_mfma_f32_16x16x32_bf16((a), (b), (c), 0, 0, 0)

// async global->LDS, 16B per lane; LDS dest = uniform base + lane*16 (linear)
static __device__ __forceinline__ void g2lds16(const u16* g, u16* l) {
    __builtin_amdgcn_global_load_lds((__attribute__((address_space(1))) void*)(void*)g,
                                     (__attribute__((address_space(3))) void*)l, 16, 0, 0);
}

// -------------------- fused f32 -> bf16 convert (q + kv) --------------------
__global__ __launch_bounds__(256) void cvt_all(const float* __restrict__ q,
                                               const float* __restrict__ kv,
                                               u16* __restrict__ qbf,
                                               u16* __restrict__ kvbf) {
    const int QN4 = B_ * QT_ * E_ / 4;  // 524288
    int i = blockIdx.x * 256 + threadIdx.x;
    const float4* s;
    ushort4* d;
    if (i < QN4) {
        s = reinterpret_cast<const float4*>(q) + i;
        d = reinterpret_cast<ushort4*>(qbf) + i;
    } else {
        int j = i - QN4;
        s = reinterpret_cast<const float4*>(kv) + j;
        d = reinterpret_cast<ushort4*>(kvbf) + j;
    }
    float4 v = *s;
    ushort4 o;
    o.x = f2bf(v.x); o.y = f2bf(v.y); o.z = f2bf(v.z); o.w = f2bf(v.w);
    *d = o;
}

// -------------------- batched weight transpose: wt4[z][n][k] = bf16(Wz[k][n]) ------------
__global__ __launch_bounds__(256) void wt_all(const float* __restrict__ Wq,
                                              const float* __restrict__ Wk,
                                              const float* __restrict__ Wv,
                                              const float* __restrict__ Wo,
                                              u16* __restrict__ wt4) {
    __shared__ float t[64][65];
    const float* W = (blockIdx.z == 0) ? Wq : (blockIdx.z == 1) ? Wk : (blockIdx.z == 2) ? Wv : Wo;
    u16* dst = wt4 + (size_t)blockIdx.z * E_ * E_;
    int k0 = blockIdx.x * 64, n0 = blockIdx.y * 64;
    int tid = threadIdx.x;
#pragma unroll
    for (int i = 0; i < 16; i++) {
        int idx = tid + i * 256, r = idx >> 6, c = idx & 63;
        t[r][c] = W[(k0 + r) * E_ + n0 + c];
    }
    __syncthreads();
#pragma unroll
    for (int i = 0; i < 16; i++) {
        int idx = tid + i * 256, r = idx >> 6, c = idx & 63;
        dst[(n0 + r) * E_ + k0 + c] = f2bf(t[c][r]);
    }
}

// -------------------- fused RoPE tables (reference quirk: freq index = d>>2) ----------
__global__ __launch_bounds__(256) void rope_all(const int* __restrict__ qpos,
                                                const int* __restrict__ kvpos,
                                                float2* __restrict__ tq,
                                                float2* __restrict__ tk) {
    const int QROWS = B_ * QT_;  // 4096
    int i = blockIdx.x * 256 + threadIdx.x;  // 196608 total
    int k = i & 15, row = i >> 4;
    float fr = exp2f((float)k * -0.41524101186092028f);  // log2(10000)/32
    int p;
    float2* dst;
    if (row < QROWS) { p = qpos[row]; dst = tq + i; }
    else { p = kvpos[row - QROWS]; dst = tk + (i - QROWS * 16); }
    float sn, cs;
    sincosf((float)p * fr, &sn, &cs);
    *dst = make_float2(cs, sn);
}

// -------------------- fused Q+K+V projection GEMM (BK=32: 32KB LDS, all 640 resident) ----
// 640 blocks: 128 Q-role (M=4096,N=512) + 512 KV-role (M=8192,N=1024 fused K|V).
// Q epilogue: RoPE * 0.125 -> qhh [B,H,QT,64]; K: RoPE -> khh; V: tiled vt [bh][n/64][d][64]
__global__ __launch_bounds__(256) void proj_qkv(const u16* __restrict__ qbf,
                                                const u16* __restrict__ kvbf,
                                                const u16* __restrict__ wt4,
                                                const float* __restrict__ bq,
                                                const float* __restrict__ bk,
                                                const float* __restrict__ bv,
                                                u16* __restrict__ qhh,
                                                u16* __restrict__ khh,
                                                u16* __restrict__ vt,
                                                const float2* __restrict__ tq,
                                                const float2* __restrict__ tk) {
    __shared__ __align__(16) u16 la[2][128 * 32];
    __shared__ __align__(16) u16 lb[2][128 * 32];

    const int id = blockIdx.x;
    const int sw = (id & 7) * 80 + (id >> 3);  // bijective XCD swizzle over 640
    const bool isQ = (sw < 128);
    int m0, n0;
    const u16 *X, *W;
    if (isQ) { m0 = (sw >> 2) * 128; n0 = (sw & 3) * 128; X = qbf; W = wt4; }
    else { const int s2 = sw - 128; m0 = (s2 >> 3) * 128; n0 = (s2 & 7) * 128; X = kvbf; W = wt4 + 512 * 512; }

    const int tid = threadIdx.x, w = tid >> 6, lane = tid & 63;
    const int lr = lane & 15, lg = lane >> 4;
    const int wml = (w >> 1) * 64, wnl = (w & 1) * 64;

    auto stage = [&](const u16* gsrc, u16* lbuf) {
#pragma unroll
        for (int i = 0; i < 2; i++) {
            const int r0 = w * 32 + i * 16;
            const int row = r0 + (lane >> 2);
            const u16* src = gsrc + row * E_ + (((lane & 3) ^ (row & 3)) * 8);
            g2lds16(src, lbuf + r0 * 32);
        }
    };

    f32x4 acc[4][4];
#pragma unroll
    for (int i = 0; i < 4; i++)
#pragma unroll
        for (int j = 0; j < 4; j++) acc[i][j] = f32x4{0.f, 0.f, 0.f, 0.f};

    stage(X + m0 * E_, la[0]);
    stage(W + n0 * E_, lb[0]);
    __syncthreads();
    int buf = 0;
    for (int kt = 0; kt < E_ / 32; kt++) {
        if (kt + 1 < E_ / 32) {
            stage(X + m0 * E_ + (kt + 1) * 32, la[buf ^ 1]);
            stage(W + n0 * E_ + (kt + 1) * 32, lb[buf ^ 1]);
        }
        bf16x8 a[4], bb[4];
#pragma unroll
        for (int mb = 0; mb < 4; mb++) {
            const int r = wml + mb * 16 + lr;
            a[mb] = ldbf8(la[buf] + r * 32 + ((lg ^ (r & 3)) * 8));
        }
#pragma unroll
        for (int nb = 0; nb < 4; nb++) {
            const int r = wnl + nb * 16 + lr;
            bb[nb] = ldbf8(lb[buf] + r * 32 + ((lg ^ (r & 3)) * 8));
        }
        __builtin_amdgcn_s_setprio(1);
#pragma unroll
        for (int mb = 0; mb < 4; mb++)
#pragma unroll
            for (int nb = 0; nb < 4; nb++)
                acc[mb][nb] = MFMA16(a[mb], bb[nb], acc[mb][nb]);
        __builtin_amdgcn_s_setprio(0);
        __syncthreads();
        buf ^= 1;
    }

    const bool isV = !isQ && (n0 >= 512);  // wg-uniform
#pragma unroll
    for (int mb = 0; mb < 4; mb++) {
#pragma unroll
        for (int nb = 0; nb < 4; nb++) {
            const int col = n0 + wnl + nb * 16 + lr;  // C col = lane&15
            const float bs = isQ ? bq[col] : (isV ? bv[col - 512] : bk[col]);
#pragma unroll
            for (int r = 0; r < 4; r++) {
                const int row = m0 + wml + mb * 16 + lg * 4 + r;  // C row = (lane>>4)*4+reg
                float v = acc[mb][nb][r] + bs;
                if (isV) {
                    const int cv = col - 512, d = cv & 63, h = cv >> 6;
                    const int b = row >> 11, n = row & 2047;
                    vt[(((b * H_ + h) * (N_ / 64) + (n >> 6)) * DH_ + d) * 64 + (n & 63)] = f2bf(v);
                } else {
                    const int d = col & 63, h = col >> 6;
                    float2 t = isQ ? tq[row * 16 + (d >> 2)] : tk[row * 16 + (d >> 2)];
                    float other = __shfl_xor(v, 1);  // pair mate: col^1 lives in lane^1
                    float y = (d & 1) ? (other * t.y + v * t.x) : (v * t.x - other * t.y);
                    if (isQ) {
                        y *= 0.125f;  // softmax scale folded into Q
                        const int b = row >> 10, tok = row & 1023;
                        qhh[((b * H_ + h) * QT_ + tok) * DH_ + d] = f2bf(y);
                    } else {
                        const int b = row >> 11, tok = row & 2047;
                        khh[((b * H_ + h) * N_ + tok) * DH_ + d] = f2bf(y);
                    }
                }
            }
        }
    }
}

// -------------------- attn pass A: partial row sums of exp(score) (staged, proven) ------
// grid 2048 (XCD-swizzled): (bh, qt, ns). wg = 64 q (4 waves x 16) x 512 kv (8 tiles).
// K staged via global_load_lds (dbuf 16KB) - prefetch pipeline. Writes sums4[..*4+ns].
__global__ __launch_bounds__(256) void attn_sums(const u16* __restrict__ qh,
                                                 const u16* __restrict__ kh,
                                                 const int* __restrict__ kv_mask,
                                                 float* __restrict__ sums4) {
    __shared__ __align__(16) u16 kbuf[2][64 * 64];

    const int id = blockIdx.x;
    const int sw = (id & 7) * 256 + (id >> 3);  // XCD k gets 4 consecutive bh
    const int bh = sw >> 6, qt = (sw >> 2) & 15, ns = sw & 3;
    const int b = bh >> 3;
    const int tid = threadIdx.x, w = tid >> 6, lane = tid & 63;
    const int lr = lane & 15, lg = lane >> 4;
    const int q0 = qt * 64 + w * 16;

    const u16* qbase = qh + (bh * QT_ + q0) * DH_;
    const bf16x8 qf0 = ldbf8(qbase + lr * DH_ + lg * 8);   // Q pre-scaled by 0.125
    const bf16x8 qf1 = ldbf8(qbase + lr * DH_ + 32 + lg * 8);
    const u16* kbase = kh + (size_t)bh * (N_ * DH_) + ns * 512 * DH_;
    const int* mbase = kv_mask + b * N_ + ns * 512;

    auto stage = [&](const u16* gsrc, u16* lbuf) {
#pragma unroll
        for (int i = 0; i < 2; i++) {
            const int r0 = w * 16 + i * 8;
            const int row = r0 + (lane >> 3);
            const u16* src = gsrc + row * 64 + (((lane & 7) ^ (row & 7)) * 8);
            g2lds16(src, lbuf + r0 * 64);
        }
    };

    float lsum[4] = {0.f, 0.f, 0.f, 0.f};
    stage(kbase, kbuf[0]);
    __syncthreads();
    for (int t = 0; t < 8; t++) {
        const u16* kc = kbuf[t & 1];
        if (t < 7) stage(kbase + (t + 1) * (64 * DH_), kbuf[(t + 1) & 1]);
#pragma unroll
        for (int n = 0; n < 4; n++) {
            const int krow = n * 16 + lr;
            const u16* kp = kc + krow * 64;
            bf16x8 k0 = ldbf8(kp + ((lg ^ (krow & 7)) * 8));
            bf16x8 k1 = ldbf8(kp + (((lg + 4) ^ (krow & 7)) * 8));
            f32x4 c = f32x4{0.f, 0.f, 0.f, 0.f};
            __builtin_amdgcn_s_setprio(1);
            c = MFMA16(qf0, k0, c);
            c = MFMA16(qf1, k1, c);
            __builtin_amdgcn_s_setprio(0);
            const bool keep = (mbase[t * 64 + n * 16 + lr] != 0);
#pragma unroll
            for (int r = 0; r < 4; r++) lsum[r] += keep ? __expf(c[r]) : 0.f;
        }
        __syncthreads();
    }
#pragma unroll
    for (int r = 0; r < 4; r++) {
        float s = lsum[r];
        s += __shfl_xor(s, 1); s += __shfl_xor(s, 2);
        s += __shfl_xor(s, 4); s += __shfl_xor(s, 8);
        if (lr == 0) sums4[((size_t)bh * QT_ + q0 + lg * 4 + r) * 4 + ns] = s;
    }
}

// -------------------- attn pass B: write attn + partial PV (8-wave wgs) --------------------
// grid 1024 (XCD-swizzled): (bh, qt of 8, ns of 4). wg = 512 thr = 8 waves; wave w owns
// q-rows [qt*128 + w*16, +16); 8 kv-tiles of 64. K/V tiles shared by 8 waves (staging
// amortized: 2 instr/wave/tile); LDS = 16K Kdbuf + 16K Vdbuf + 16K P = 48KB -> 3 wg/CU
// = 24 waves/CU. Inner loop = R7-proven template (swizzles, P layout, store path).
__global__ __launch_bounds__(512) void attn_pv(const u16* __restrict__ qh,
                                               const u16* __restrict__ kh,
                                               const u16* __restrict__ vt,
                                               const int* __restrict__ kv_mask,
                                               const float* __restrict__ sums4,
                                               float* __restrict__ attn_out,
                                               float* __restrict__ pvpart) {
    __shared__ __align__(16) u16 kbuf[2][64 * 64];
    __shared__ __align__(16) u16 vbuf[2][64 * 64];
    __shared__ unsigned PW[8][16][32];  // per-wave packed bf16-pair P, granule-swizzled

    const int id = blockIdx.x;
    const int sw = (id & 7) * 128 + (id >> 3);  // XCD k gets 4 consecutive bh
    const int bh = sw >> 5, qt = (sw >> 2) & 7, ns = sw & 3;
    const int b = bh >> 3;
    const int tid = threadIdx.x, w = tid >> 6, lane = tid & 63;
    const int lr = lane & 15, lg = lane >> 4;
    const int q0 = qt * 128 + w * 16;

    const u16* qbase = qh + (bh * QT_ + q0) * DH_;
    const bf16x8 qf0 = ldbf8(qbase + lr * DH_ + lg * 8);   // Q pre-scaled by 0.125
    const bf16x8 qf1 = ldbf8(qbase + lr * DH_ + 32 + lg * 8);
    const u16* kbase = kh + (size_t)bh * (N_ * DH_) + ns * 512 * DH_;
    const u16* vbase = vt + (size_t)bh * (N_ * DH_) + ns * 512 * DH_;  // [8 t][64 d][64]
    const int* mbase = kv_mask + b * N_ + ns * 512;

    // total row sums -> inv
    float inv[4];
#pragma unroll
    for (int r = 0; r < 4; r++) {
        float4 s4 = *reinterpret_cast<const float4*>(
            sums4 + ((size_t)bh * QT_ + q0 + lg * 4 + r) * 4);
        float tot = s4.x + s4.y + s4.z + s4.w;
        inv[r] = (tot > 0.f) ? (1.0f / tot) : 0.f;  // all-masked row -> attn = ctx = 0
    }

    // stage K tile [64 kv][64 d] + V tile [64 d][64 kv]: wave w stages rows [w*8, w*8+8)
    // of each (1 instr per buffer per wave). Source pre-swizzled ^(row&7).
    auto stage = [&](int t, u16* kb, u16* vb) {
        const int r0 = w * 8;
        const int row = r0 + (lane >> 3);
        const int gsw = ((lane & 7) ^ (row & 7)) * 8;
        g2lds16(kbase + (t * 64 + row) * 64 + gsw, kb + r0 * 64);
        g2lds16(vbase + (t * 64 + row) * 64 + gsw, vb + r0 * 64);
    };

    f32x4 pv[4];
#pragma unroll
    for (int i = 0; i < 4; i++) pv[i] = f32x4{0.f, 0.f, 0.f, 0.f};
    unsigned(*P)[32] = PW[w];
    float* abase = attn_out + ((size_t)(bh * QT_ + q0)) * N_ + ns * 512;
    const int srow = lane >> 4, cq = lane & 15;  // store: 4 rows x 256B per instr

    stage(0, kbuf[0], vbuf[0]);
    __syncthreads();
    for (int t = 0; t < 8; t++) {
        const u16* kc = kbuf[t & 1];
        const u16* vc = vbuf[t & 1];
        if (t < 7) stage(t + 1, kbuf[(t + 1) & 1], vbuf[(t + 1) & 1]);
#pragma unroll
        for (int n = 0; n < 4; n++) {
            const int krow = n * 16 + lr;
            const u16* kp = kc + krow * 64;
            bf16x8 k0 = ldbf8(kp + ((lg ^ (krow & 7)) * 8));
            bf16x8 k1 = ldbf8(kp + (((lg + 4) ^ (krow & 7)) * 8));
            f32x4 c = f32x4{0.f, 0.f, 0.f, 0.f};
            __builtin_amdgcn_s_setprio(1);
            c = MFMA16(qf0, k0, c);
            c = MFMA16(qf1, k1, c);
            __builtin_amdgcn_s_setprio(0);
            const bool keep = (mbase[t * 64 + n * 16 + lr] != 0);
#pragma unroll
            for (int r = 0; r < 4; r++) {
                float p = keep ? (__expf(c[r]) * inv[r]) : 0.f;  // normalized
                float hi = __shfl_xor(p, 1);
                __bf16 lo_b = (__bf16)p, hi_b = (__bf16)hi;
                unsigned pk = ((unsigned)__builtin_bit_cast(u16, hi_b) << 16) |
                              (unsigned)__builtin_bit_cast(u16, lo_b);
                if (!(lr & 1)) {
                    const int row = lg * 4 + r, c32 = n * 8 + (lr >> 1);
                    P[row][(((c32 >> 2) ^ (row & 7)) << 2) + (c32 & 3)] = pk;
                }
            }
        }
        // attn stores: read packed P (b64), unpack bf16->f32, 4 rows x 256B segments
#pragma unroll
        for (int i = 0; i < 4; i++) {
            const int row = i * 4 + srow, rw = row & 7;
            const int m = (((cq >> 1) ^ rw) << 2) + ((cq & 1) << 1);
            uint2 pp = *reinterpret_cast<const uint2*>(&P[row][m]);
            f32x4 vv;
            vv[0] = __builtin_bit_cast(float, pp.x << 16);
            vv[1] = __builtin_bit_cast(float, pp.x & 0xffff0000u);
            vv[2] = __builtin_bit_cast(float, pp.y << 16);
            vv[3] = __builtin_bit_cast(float, pp.y & 0xffff0000u);
            *reinterpret_cast<f32x4*>(abase + (size_t)row * N_ + t * 64 + cq * 4) = vv;
        }
        // PV: ctx[16q,64d] += P @ V-tile; A-frag = one swizzled b128 granule
#pragma unroll
        for (int ks = 0; ks < 2; ks++) {
            const int g = (4 * ks + lg) ^ (lr & 7);
            uint4 a4 = *reinterpret_cast<const uint4*>(&P[lr][g << 2]);
            bf16x8 af = __builtin_bit_cast(bf16x8, a4);
            __builtin_amdgcn_s_setprio(1);
#pragma unroll
            for (int nb = 0; nb < 4; nb++) {
                const int vrow = nb * 16 + lr;
                bf16x8 bv = ldbf8(vc + vrow * 64 + (((ks * 4 + lg) ^ (vrow & 7)) * 8));
                pv[nb] = MFMA16(af, bv, pv[nb]);
            }
            __builtin_amdgcn_s_setprio(0);
        }
        __syncthreads();
    }

    // partial ctx: pvpart[ns][bh][q][64]
    float* pbase = pvpart + (((size_t)ns * 32 + bh) * QT_) * DH_;
#pragma unroll
    for (int nb = 0; nb < 4; nb++)
#pragma unroll
        for (int r = 0; r < 4; r++)
            pbase[(size_t)(q0 + lg * 4 + r) * DH_ + nb * 16 + lr] = pv[nb][r];
}

// -------------------- ctx reduce: ctx[b,tok,h*64+d] = bf16(sum_ns pvpart) ------------
__global__ __launch_bounds__(256) void ctx_reduce(const float* __restrict__ pvpart,
                                                  u16* __restrict__ ctx) {
    const size_t SL = (size_t)32 * QT_ * DH_;  // slice stride (f32)
    const int i = blockIdx.x * 256 + threadIdx.x;  // 524288 threads, 4 elems each
    const int base = i * 4;
    const int d = base & 63, h = (base >> 6) & 7;
    const int bt = base >> 9;              // b*1024 + tok
    const size_t pi = (((size_t)(bt >> 10) * 8 + h) * QT_ + (bt & 1023)) * DH_ + d;
    f32x4 s0 = *reinterpret_cast<const f32x4*>(pvpart + pi);
    f32x4 s1 = *reinterpret_cast<const f32x4*>(pvpart + SL + pi);
    f32x4 s2 = *reinterpret_cast<const f32x4*>(pvpart + 2 * SL + pi);
    f32x4 s3 = *reinterpret_cast<const f32x4*>(pvpart + 3 * SL + pi);
    u16x4 o;
#pragma unroll
    for (int j = 0; j < 4; j++) o[j] = f2bf((s0[j] + s1[j]) + (s2[j] + s3[j]));
    *reinterpret_cast<u16x4*>(ctx + base) = o;
}

// -------------------- O projection: 64x64 tiles, grid 512 --------------------
__global__ __launch_bounds__(256) void proj_o(const u16* __restrict__ X,
                                              const u16* __restrict__ Wt,
                                              const float* __restrict__ bias,
                                              float* __restrict__ outp,
                                              const int* __restrict__ qmask) {
    __shared__ __align__(16) u16 la[2][64 * 64];
    __shared__ __align__(16) u16 lb[2][64 * 64];

    const int id = blockIdx.x;             // 512 blocks
    const int sw = (id & 7) * 64 + (id >> 3);
    const int m0 = (sw >> 3) * 64, n0 = (sw & 7) * 64;

    const int tid = threadIdx.x, w = tid >> 6, lane = tid & 63;
    const int lr = lane & 15, lg = lane >> 4;
    const int wml = (w >> 1) * 32, wnl = (w & 1) * 32;

    auto stage = [&](const u16* gsrc, u16* lbuf) {
#pragma unroll
        for (int i = 0; i < 2; i++) {
            const int r0 = w * 16 + i * 8;
            const int row = r0 + (lane >> 3);
            const u16* src = gsrc + row * E_ + (((lane & 7) ^ (row & 7)) * 8);
            g2lds16(src, lbuf + r0 * 64);
        }
    };

    f32x4 acc[2][2];
#pragma unroll
    for (int i = 0; i < 2; i++)
#pragma unroll
        for (int j = 0; j < 2; j++) acc[i][j] = f32x4{0.f, 0.f, 0.f, 0.f};

    stage(X + m0 * E_, la[0]);
    stage(Wt + n0 * E_, lb[0]);
    __syncthreads();
    int buf = 0;
    for (int kt = 0; kt < E_ / 64; kt++) {
        if (kt + 1 < E_ / 64) {
            stage(X + m0 * E_ + (kt + 1) * 64, la[buf ^ 1]);
            stage(Wt + n0 * E_ + (kt + 1) * 64, lb[buf ^ 1]);
        }
#pragma unroll
        for (int ks = 0; ks < 2; ks++) {
            bf16x8 a[2], bb[2];
#pragma unroll
            for (int mb = 0; mb < 2; mb++) {
                const int r = wml + mb * 16 + lr;
                a[mb] = ldbf8(la[buf] + r * 64 + (((ks * 4 + lg) ^ (r & 7)) * 8));
            }
#pragma unroll
            for (int nb = 0; nb < 2; nb++) {
                const int r = wnl + nb * 16 + lr;
                bb[nb] = ldbf8(lb[buf] + r * 64 + (((ks * 4 + lg) ^ (r & 7)) * 8));
            }
            __builtin_amdgcn_s_setprio(1);
#pragma unroll
            for (int mb = 0; mb < 2; mb++)
#pragma unroll
                for (int nb = 0; nb < 2; nb++)
                    acc[mb][nb] = MFMA16(a[mb], bb[nb], acc[mb][nb]);
            __builtin_amdgcn_s_setprio(0);
        }
        __syncthreads();
        buf ^= 1;
    }

#pragma unroll
    for (int mb = 0; mb < 2; mb++) {
#pragma unroll
        for (int nb = 0; nb < 2; nb++) {
            const int col = n0 + wnl + nb * 16 + lr;
            const float bs = bias[col];
#pragma unroll
            for (int r = 0; r < 4; r++) {
                const int row = m0 + wml + mb * 16 + lg * 4 + r;
                float v = acc[mb][nb][r] + bs;
                float m = (qmask[row] != 0) ? 1.0f : 0.0f;
                outp[row * E_ + col] = v * m;
            }
        }
    }
}

// -------------------- host launch --------------------
extern "C" void kernel_launch(void* const* d_in, const int* in_sizes, int n_in,
                              void* d_out, int out_size, void* d_ws, size_t ws_size,
                              hipStream_t stream) {
    (void)in_sizes; (void)n_in; (void)out_size; (void)ws_size;
    const float* q   = (const float*)d_in[0];
    const float* kv  = (const float*)d_in[1];
    const int* q_mask  = (const int*)d_in[2];
    const int* kv_mask = (const int*)d_in[3];
    const int* q_pos   = (const int*)d_in[4];
    const int* kv_pos  = (const int*)d_in[5];
    const float* Wq = (const float*)d_in[6];  const float* bq = (const float*)d_in[7];
    const float* Wk = (const float*)d_in[8];  const float* bk = (const float*)d_in[9];
    const float* Wv = (const float*)d_in[10]; const float* bv = (const float*)d_in[11];
    const float* Wo = (const float*)d_in[12]; const float* bo = (const float*)d_in[13];
    float* outp = (float*)d_out;

    char* ws = (char*)d_ws;
    size_t off = 0;
    auto carve = [&](size_t bytes) -> void* {
        void* p = ws + off;
        off = (off + bytes + 255) & ~(size_t)255;
        return p;
    };
    u16* qbf    = (u16*)carve((size_t)B_ * QT_ * E_ * 2);
    u16* kvbf   = (u16*)carve((size_t)B_ * N_ * E_ * 2);
    u16* wt4    = (u16*)carve((size_t)4 * E_ * E_ * 2);  // [Wq^T|Wk^T|Wv^T|Wo^T]
    u16* qhh    = (u16*)carve((size_t)B_ * H_ * QT_ * DH_ * 2);
    u16* khh    = (u16*)carve((size_t)B_ * H_ * N_ * DH_ * 2);
    u16* vt     = (u16*)carve((size_t)B_ * H_ * DH_ * N_ * 2);  // tiled [bh][32][64][64]
    u16* ctx    = (u16*)carve((size_t)B_ * QT_ * E_ * 2);
    float2* tq  = (float2*)carve((size_t)B_ * QT_ * 16 * sizeof(float2));
    float2* tk  = (float2*)carve((size_t)B_ * N_ * 16 * sizeof(float2));
    float* sums4  = (float*)carve((size_t)B_ * H_ * QT_ * 4 * sizeof(float));
    float* pvpart = (float*)carve((size_t)4 * B_ * H_ * QT_ * DH_ * sizeof(float));

    cvt_all<<<6144, 256, 0, stream>>>(q, kv, qbf, kvbf);
    wt_all<<<dim3(8, 8, 4), 256, 0, stream>>>(Wq, Wk, Wv, Wo, wt4);
    rope_all<<<768, 256, 0, stream>>>(q_pos, kv_pos, tq, tk);

    proj_qkv<<<640, 256, 0, stream>>>(qbf, kvbf, wt4, bq, bk, bv, qhh, khh, vt, tq, tk);

    attn_sums<<<2048, 256, 0, stream>>>(qhh, khh, kv_mask, sums4);
    attn_pv<<<1024, 512, 0, stream>>>(qhh, khh, vt, kv_mask, sums4,
                                      outp + (size_t)B_ * QT_ * E_, pvpart);
    ctx_reduce<<<2048, 256, 0, stream>>>(pvpart, ctx);

    proj_o<<<512, 256, 0, stream>>>(ctx, wt4 + 3 * 512 * 512, bo, outp, q_mask);
}

// Round 12
// 153.482 us; speedup vs baseline: 1.8281x; 1.0357x over previous
//
#include <hip/hip_runtime.h>
#include <hip/hip_bf16.h>

// Problem constants (CrossEncoder): B=4, QT=1024, N=2048, E=512, H=8, Dh=64
#define B_  4
#define QT_ 1024
#define N_  2048
#define E_  512
#define H_  8
#define DH_ 64

typedef float  f32x4  __attribute__((ext_vector_type(4)));
typedef __bf16 bf16x8 __attribute__((ext_vector_type(8)));
typedef unsigned short u16;
typedef u16 u16x4 __attribute__((ext_vector_type(4)));

// round-to-nearest-even f32 -> bf16
static __device__ __forceinline__ u16 f2bf(float f) {
    unsigned u = __builtin_bit_cast(unsigned, f);
    return (u16)((u + 0x7fffu + ((u >> 16) & 1u)) >> 16);
}

static __device__ __forceinline__ bf16x8 ldbf8(const u16* p) {
    uint4 v = *reinterpret_cast<const uint4*>(p);
    return __builtin_bit_cast(bf16x8, v);
}

#define MFMA16(a, b, c) __builtin_amdgcn_mfma_f32_16x16x32_bf16((a), (b), (c), 0, 0, 0)

// async global->LDS, 16B per lane; LDS dest = uniform base + lane*16 (linear)
static __device__ __forceinline__ void g2lds16(const u16* g, u16* l) {
    __builtin_amdgcn_global_load_lds((__attribute__((address_space(1))) void*)(void*)g,
                                     (__attribute__((address_space(3))) void*)l, 16, 0, 0);
}

// -------------------- fused prep: cvt (6144 blk) + wt (256 blk) + rope (768 blk) --------
__global__ __launch_bounds__(256) void prep_all(const float* __restrict__ q,
                                                const float* __restrict__ kv,
                                                const float* __restrict__ Wq,
                                                const float* __restrict__ Wk,
                                                const float* __restrict__ Wv,
                                                const float* __restrict__ Wo,
                                                const int* __restrict__ qpos,
                                                const int* __restrict__ kvpos,
                                                u16* __restrict__ qbf,
                                                u16* __restrict__ kvbf,
                                                u16* __restrict__ wt4,
                                                float2* __restrict__ tq,
                                                float2* __restrict__ tk) {
    __shared__ float t[64][65];
    const int bid = blockIdx.x, tid = threadIdx.x;
    if (bid < 6144) {
        // f32 -> bf16 convert (q then kv)
        const int QN4 = B_ * QT_ * E_ / 4;  // 524288
        int i = bid * 256 + tid;
        const float4* s;
        ushort4* d;
        if (i < QN4) {
            s = reinterpret_cast<const float4*>(q) + i;
            d = reinterpret_cast<ushort4*>(qbf) + i;
        } else {
            int j = i - QN4;
            s = reinterpret_cast<const float4*>(kv) + j;
            d = reinterpret_cast<ushort4*>(kvbf) + j;
        }
        float4 v = *s;
        ushort4 o;
        o.x = f2bf(v.x); o.y = f2bf(v.y); o.z = f2bf(v.z); o.w = f2bf(v.w);
        *d = o;
    } else if (bid < 6400) {
        // weight transpose+convert: wt4[z][n][k] = bf16(Wz[k][n])
        const int idx = bid - 6144;
        const int z = idx >> 6, rem = idx & 63, xb = rem & 7, yb = rem >> 3;
        const float* W = (z == 0) ? Wq : (z == 1) ? Wk : (z == 2) ? Wv : Wo;
        u16* dst = wt4 + (size_t)z * E_ * E_;
        const int k0 = xb * 64, n0 = yb * 64;
#pragma unroll
        for (int i = 0; i < 16; i++) {
            int ix = tid + i * 256, r = ix >> 6, c = ix & 63;
            t[r][c] = W[(k0 + r) * E_ + n0 + c];
        }
        __syncthreads();
#pragma unroll
        for (int i = 0; i < 16; i++) {
            int ix = tid + i * 256, r = ix >> 6, c = ix & 63;
            dst[(n0 + r) * E_ + k0 + c] = f2bf(t[c][r]);
        }
    } else {
        // RoPE tables (reference quirk: freq index = d>>2 -> 16 freqs)
        const int QROWS = B_ * QT_;  // 4096
        int i = (bid - 6400) * 256 + tid;  // 196608 total
        int k = i & 15, row = i >> 4;
        float fr = exp2f((float)k * -0.41524101186092028f);  // log2(10000)/32
        int p;
        float2* dst;
        if (row < QROWS) { p = qpos[row]; dst = tq + i; }
        else { p = kvpos[row - QROWS]; dst = tk + (i - QROWS * 16); }
        float sn, cs;
        sincosf((float)p * fr, &sn, &cs);
        *dst = make_float2(cs, sn);
    }
}

// -------------------- fused Q+K+V projection GEMM (BK=32: 32KB LDS, all 640 resident) ----
// 640 blocks: 128 Q-role (M=4096,N=512) + 512 KV-role (M=8192,N=1024 fused K|V).
// Q epilogue: RoPE * 0.125 -> qhh [B,H,QT,64]; K: RoPE -> khh; V: tiled vt [bh][n/64][d][64]
__global__ __launch_bounds__(256) void proj_qkv(const u16* __restrict__ qbf,
                                                const u16* __restrict__ kvbf,
                                                const u16* __restrict__ wt4,
                                                const float* __restrict__ bq,
                                                const float* __restrict__ bk,
                                                const float* __restrict__ bv,
                                                u16* __restrict__ qhh,
                                                u16* __restrict__ khh,
                                                u16* __restrict__ vt,
                                                const float2* __restrict__ tq,
                                                const float2* __restrict__ tk) {
    __shared__ __align__(16) u16 la[2][128 * 32];
    __shared__ __align__(16) u16 lb[2][128 * 32];

    const int id = blockIdx.x;
    const int sw = (id & 7) * 80 + (id >> 3);  // bijective XCD swizzle over 640
    const bool isQ = (sw < 128);
    int m0, n0;
    const u16 *X, *W;
    if (isQ) { m0 = (sw >> 2) * 128; n0 = (sw & 3) * 128; X = qbf; W = wt4; }
    else { const int s2 = sw - 128; m0 = (s2 >> 3) * 128; n0 = (s2 & 7) * 128; X = kvbf; W = wt4 + 512 * 512; }

    const int tid = threadIdx.x, w = tid >> 6, lane = tid & 63;
    const int lr = lane & 15, lg = lane >> 4;
    const int wml = (w >> 1) * 64, wnl = (w & 1) * 64;

    auto stage = [&](const u16* gsrc, u16* lbuf) {
#pragma unroll
        for (int i = 0; i < 2; i++) {
            const int r0 = w * 32 + i * 16;
            const int row = r0 + (lane >> 2);
            const u16* src = gsrc + row * E_ + (((lane & 3) ^ (row & 3)) * 8);
            g2lds16(src, lbuf + r0 * 32);
        }
    };

    f32x4 acc[4][4];
#pragma unroll
    for (int i = 0; i < 4; i++)
#pragma unroll
        for (int j = 0; j < 4; j++) acc[i][j] = f32x4{0.f, 0.f, 0.f, 0.f};

    stage(X + m0 * E_, la[0]);
    stage(W + n0 * E_, lb[0]);
    __syncthreads();
    int buf = 0;
    for (int kt = 0; kt < E_ / 32; kt++) {
        if (kt + 1 < E_ / 32) {
            stage(X + m0 * E_ + (kt + 1) * 32, la[buf ^ 1]);
            stage(W + n0 * E_ + (kt + 1) * 32, lb[buf ^ 1]);
        }
        bf16x8 a[4], bb[4];
#pragma unroll
        for (int mb = 0; mb < 4; mb++) {
            const int r = wml + mb * 16 + lr;
            a[mb] = ldbf8(la[buf] + r * 32 + ((lg ^ (r & 3)) * 8));
        }
#pragma unroll
        for (int nb = 0; nb < 4; nb++) {
            const int r = wnl + nb * 16 + lr;
            bb[nb] = ldbf8(lb[buf] + r * 32 + ((lg ^ (r & 3)) * 8));
        }
        __builtin_amdgcn_s_setprio(1);
#pragma unroll
        for (int mb = 0; mb < 4; mb++)
#pragma unroll
            for (int nb = 0; nb < 4; nb++)
                acc[mb][nb] = MFMA16(a[mb], bb[nb], acc[mb][nb]);
        __builtin_amdgcn_s_setprio(0);
        __syncthreads();
        buf ^= 1;
    }

    const bool isV = !isQ && (n0 >= 512);  // wg-uniform
#pragma unroll
    for (int mb = 0; mb < 4; mb++) {
#pragma unroll
        for (int nb = 0; nb < 4; nb++) {
            const int col = n0 + wnl + nb * 16 + lr;  // C col = lane&15
            const float bs = isQ ? bq[col] : (isV ? bv[col - 512] : bk[col]);
#pragma unroll
            for (int r = 0; r < 4; r++) {
                const int row = m0 + wml + mb * 16 + lg * 4 + r;  // C row = (lane>>4)*4+reg
                float v = acc[mb][nb][r] + bs;
                if (isV) {
                    const int cv = col - 512, d = cv & 63, h = cv >> 6;
                    const int b = row >> 11, n = row & 2047;
                    vt[(((b * H_ + h) * (N_ / 64) + (n >> 6)) * DH_ + d) * 64 + (n & 63)] = f2bf(v);
                } else {
                    const int d = col & 63, h = col >> 6;
                    float2 t = isQ ? tq[row * 16 + (d >> 2)] : tk[row * 16 + (d >> 2)];
                    float other = __shfl_xor(v, 1);  // pair mate: col^1 lives in lane^1
                    float y = (d & 1) ? (other * t.y + v * t.x) : (v * t.x - other * t.y);
                    if (isQ) {
                        y *= 0.125f;  // softmax scale folded into Q
                        const int b = row >> 10, tok = row & 1023;
                        qhh[((b * H_ + h) * QT_ + tok) * DH_ + d] = f2bf(y);
                    } else {
                        const int b = row >> 11, tok = row & 2047;
                        khh[((b * H_ + h) * N_ + tok) * DH_ + d] = f2bf(y);
                    }
                }
            }
        }
    }
}

// -------------------- attn pass A: partial row sums of exp(score) (staged, proven) ------
// grid 2048 (XCD-swizzled): (bh, qt, ns). wg = 64 q (4 waves x 16) x 512 kv (8 tiles).
// K staged via global_load_lds (dbuf 16KB) - prefetch pipeline. Writes sums4[..*4+ns].
__global__ __launch_bounds__(256) void attn_sums(const u16* __restrict__ qh,
                                                 const u16* __restrict__ kh,
                                                 const int* __restrict__ kv_mask,
                                                 float* __restrict__ sums4) {
    __shared__ __align__(16) u16 kbuf[2][64 * 64];

    const int id = blockIdx.x;
    const int sw = (id & 7) * 256 + (id >> 3);  // XCD k gets 4 consecutive bh
    const int bh = sw >> 6, qt = (sw >> 2) & 15, ns = sw & 3;
    const int b = bh >> 3;
    const int tid = threadIdx.x, w = tid >> 6, lane = tid & 63;
    const int lr = lane & 15, lg = lane >> 4;
    const int q0 = qt * 64 + w * 16;

    const u16* qbase = qh + (bh * QT_ + q0) * DH_;
    const bf16x8 qf0 = ldbf8(qbase + lr * DH_ + lg * 8);   // Q pre-scaled by 0.125
    const bf16x8 qf1 = ldbf8(qbase + lr * DH_ + 32 + lg * 8);
    const u16* kbase = kh + (size_t)bh * (N_ * DH_) + ns * 512 * DH_;
    const int* mbase = kv_mask + b * N_ + ns * 512;

    auto stage = [&](const u16* gsrc, u16* lbuf) {
#pragma unroll
        for (int i = 0; i < 2; i++) {
            const int r0 = w * 16 + i * 8;
            const int row = r0 + (lane >> 3);
            const u16* src = gsrc + row * 64 + (((lane & 7) ^ (row & 7)) * 8);
            g2lds16(src, lbuf + r0 * 64);
        }
    };

    float lsum[4] = {0.f, 0.f, 0.f, 0.f};
    stage(kbase, kbuf[0]);
    __syncthreads();
    for (int t = 0; t < 8; t++) {
        const u16* kc = kbuf[t & 1];
        if (t < 7) stage(kbase + (t + 1) * (64 * DH_), kbuf[(t + 1) & 1]);
#pragma unroll
        for (int n = 0; n < 4; n++) {
            const int krow = n * 16 + lr;
            const u16* kp = kc + krow * 64;
            bf16x8 k0 = ldbf8(kp + ((lg ^ (krow & 7)) * 8));
            bf16x8 k1 = ldbf8(kp + (((lg + 4) ^ (krow & 7)) * 8));
            f32x4 c = f32x4{0.f, 0.f, 0.f, 0.f};
            __builtin_amdgcn_s_setprio(1);
            c = MFMA16(qf0, k0, c);
            c = MFMA16(qf1, k1, c);
            __builtin_amdgcn_s_setprio(0);
            const bool keep = (mbase[t * 64 + n * 16 + lr] != 0);
#pragma unroll
            for (int r = 0; r < 4; r++) lsum[r] += keep ? __expf(c[r]) : 0.f;
        }
        __syncthreads();
    }
#pragma unroll
    for (int r = 0; r < 4; r++) {
        float s = lsum[r];
        s += __shfl_xor(s, 1); s += __shfl_xor(s, 2);
        s += __shfl_xor(s, 4); s += __shfl_xor(s, 8);
        if (lr == 0) sums4[((size_t)bh * QT_ + q0 + lg * 4 + r) * 4 + ns] = s;
    }
}

// -------------------- attn pass B: write attn + partial PV (8 waves x 32 q-rows) ----------
// grid 512 (XCD-swizzled): (bh, qt of 4, ns of 4). wg = 512 thr = 8 waves; wave w owns
// q-rows [qt*256 + w*32, +32) as TWO 16-row A-blocks -> K and V LDS fragments are read
// ONCE and reused for both blocks (per-16q LDS b128 reads 18 -> 10). LDS = 16K Kdbuf +
// 16K Vdbuf + 32K P = 64KB -> 2 wg/CU (grid exactly 2/CU), 16 waves/CU, VGPR<=128.
__global__ __launch_bounds__(512, 4) void attn_pv(const u16* __restrict__ qh,
                                                  const u16* __restrict__ kh,
                                                  const u16* __restrict__ vt,
                                                  const int* __restrict__ kv_mask,
                                                  const float* __restrict__ sums4,
                                                  float* __restrict__ attn_out,
                                                  float* __restrict__ pvpart) {
    __shared__ __align__(16) u16 kbuf[2][64 * 64];
    __shared__ __align__(16) u16 vbuf[2][64 * 64];
    __shared__ unsigned PW[8][32][32];  // per-wave packed bf16-pair P (32 q), granule-swz

    const int id = blockIdx.x;
    const int sw = (id & 7) * 64 + (id >> 3);   // XCD k gets 4 consecutive bh
    const int bh = sw >> 4, qt = (sw >> 2) & 3, ns = sw & 3;
    const int b = bh >> 3;
    const int tid = threadIdx.x, w = tid >> 6, lane = tid & 63;
    const int lr = lane & 15, lg = lane >> 4;
    const int q0 = qt * 256 + w * 32;

    const u16* qbase = qh + (bh * QT_ + q0) * DH_;
    bf16x8 qf[2][2];
#pragma unroll
    for (int mq = 0; mq < 2; mq++) {
        qf[mq][0] = ldbf8(qbase + (mq * 16 + lr) * DH_ + lg * 8);       // Q pre-scaled
        qf[mq][1] = ldbf8(qbase + (mq * 16 + lr) * DH_ + 32 + lg * 8);
    }
    const u16* kbase = kh + (size_t)bh * (N_ * DH_) + ns * 512 * DH_;
    const u16* vbase = vt + (size_t)bh * (N_ * DH_) + ns * 512 * DH_;  // [8 t][64 d][64]
    const int* mbase = kv_mask + b * N_ + ns * 512;

    // total row sums -> inv
    float inv[2][4];
#pragma unroll
    for (int mq = 0; mq < 2; mq++)
#pragma unroll
        for (int r = 0; r < 4; r++) {
            float4 s4 = *reinterpret_cast<const float4*>(
                sums4 + ((size_t)bh * QT_ + q0 + mq * 16 + lg * 4 + r) * 4);
            float tot = s4.x + s4.y + s4.z + s4.w;
            inv[mq][r] = (tot > 0.f) ? (1.0f / tot) : 0.f;  // all-masked -> attn = ctx = 0
        }

    // stage K tile [64 kv][64 d] + V tile [64 d][64 kv]: wave w stages rows [w*8, w*8+8)
    // of each (1 instr per buffer per wave). Source pre-swizzled ^(row&7).
    auto stage = [&](int t, u16* kb, u16* vb) {
        const int r0 = w * 8;
        const int row = r0 + (lane >> 3);
        const int gsw = ((lane & 7) ^ (row & 7)) * 8;
        g2lds16(kbase + (t * 64 + row) * 64 + gsw, kb + r0 * 64);
        g2lds16(vbase + (t * 64 + row) * 64 + gsw, vb + r0 * 64);
    };

    f32x4 pv[2][4];
#pragma unroll
    for (int mq = 0; mq < 2; mq++)
#pragma unroll
        for (int i = 0; i < 4; i++) pv[mq][i] = f32x4{0.f, 0.f, 0.f, 0.f};
    unsigned(*P)[32] = PW[w];
    float* abase = attn_out + ((size_t)(bh * QT_ + q0)) * N_ + ns * 512;
    const int srow = lane >> 4, cq = lane & 15;  // store: 4 rows x 256B per instr

    stage(0, kbuf[0], vbuf[0]);
    __syncthreads();
    for (int t = 0; t < 8; t++) {
        const u16* kc = kbuf[t & 1];
        const u16* vc = vbuf[t & 1];
        if (t < 7) stage(t + 1, kbuf[(t + 1) & 1], vbuf[(t + 1) & 1]);
#pragma unroll
        for (int n = 0; n < 4; n++) {
            const int krow = n * 16 + lr;
            const u16* kp = kc + krow * 64;
            bf16x8 k0 = ldbf8(kp + ((lg ^ (krow & 7)) * 8));
            bf16x8 k1 = ldbf8(kp + (((lg + 4) ^ (krow & 7)) * 8));
            f32x4 c0 = f32x4{0.f, 0.f, 0.f, 0.f};
            f32x4 c1 = f32x4{0.f, 0.f, 0.f, 0.f};
            __builtin_amdgcn_s_setprio(1);
            c0 = MFMA16(qf[0][0], k0, c0);
            c0 = MFMA16(qf[0][1], k1, c0);
            c1 = MFMA16(qf[1][0], k0, c1);
            c1 = MFMA16(qf[1][1], k1, c1);
            __builtin_amdgcn_s_setprio(0);
            const bool keep = (mbase[t * 64 + krow] != 0);
#pragma unroll
            for (int mq = 0; mq < 2; mq++) {
#pragma unroll
                for (int r = 0; r < 4; r++) {
                    float p = keep ? (__expf((mq ? c1 : c0)[r]) * inv[mq][r]) : 0.f;
                    float hi = __shfl_xor(p, 1);
                    __bf16 lo_b = (__bf16)p, hi_b = (__bf16)hi;
                    unsigned pk = ((unsigned)__builtin_bit_cast(u16, hi_b) << 16) |
                                  (unsigned)__builtin_bit_cast(u16, lo_b);
                    if (!(lr & 1)) {
                        const int row = mq * 16 + lg * 4 + r, c32 = n * 8 + (lr >> 1);
                        P[row][(((c32 >> 2) ^ (row & 7)) << 2) + (c32 & 3)] = pk;
                    }
                }
            }
        }
        // attn stores: read packed P (b64), unpack bf16->f32, 4 rows x 256B segments
#pragma unroll
        for (int i = 0; i < 8; i++) {
            const int row = i * 4 + srow, rw = row & 7;
            const int m = (((cq >> 1) ^ rw) << 2) + ((cq & 1) << 1);
            uint2 pp = *reinterpret_cast<const uint2*>(&P[row][m]);
            f32x4 vv;
            vv[0] = __builtin_bit_cast(float, pp.x << 16);
            vv[1] = __builtin_bit_cast(float, pp.x & 0xffff0000u);
            vv[2] = __builtin_bit_cast(float, pp.y << 16);
            vv[3] = __builtin_bit_cast(float, pp.y & 0xffff0000u);
            *reinterpret_cast<f32x4*>(abase + (size_t)row * N_ + t * 64 + cq * 4) = vv;
        }
        // PV: ctx[32q,64d] += P @ V-tile; V b128 frags loaded once, reused for both mq
#pragma unroll
        for (int ks = 0; ks < 2; ks++) {
            bf16x8 bv[4];
#pragma unroll
            for (int nb = 0; nb < 4; nb++) {
                const int vrow = nb * 16 + lr;
                bv[nb] = ldbf8(vc + vrow * 64 + (((ks * 4 + lg) ^ (vrow & 7)) * 8));
            }
            const int g = (4 * ks + lg) ^ (lr & 7);
#pragma unroll
            for (int mq = 0; mq < 2; mq++) {
                uint4 a4 = *reinterpret_cast<const uint4*>(&P[mq * 16 + lr][g << 2]);
                bf16x8 af = __builtin_bit_cast(bf16x8, a4);
                __builtin_amdgcn_s_setprio(1);
#pragma unroll
                for (int nb = 0; nb < 4; nb++)
                    pv[mq][nb] = MFMA16(af, bv[nb], pv[mq][nb]);
                __builtin_amdgcn_s_setprio(0);
            }
        }
        __syncthreads();
    }

    // partial ctx: pvpart[ns][bh][q][64]
    float* pbase = pvpart + (((size_t)ns * 32 + bh) * QT_) * DH_;
#pragma unroll
    for (int mq = 0; mq < 2; mq++)
#pragma unroll
        for (int nb = 0; nb < 4; nb++)
#pragma unroll
            for (int r = 0; r < 4; r++)
                pbase[(size_t)(q0 + mq * 16 + lg * 4 + r) * DH_ + nb * 16 + lr] = pv[mq][nb][r];
}

// -------------------- ctx reduce: ctx[b,tok,h*64+d] = bf16(sum_ns pvpart) ------------
__global__ __launch_bounds__(256) void ctx_reduce(const float* __restrict__ pvpart,
                                                  u16* __restrict__ ctx) {
    const size_t SL = (size_t)32 * QT_ * DH_;  // slice stride (f32)
    const int i = blockIdx.x * 256 + threadIdx.x;  // 524288 threads, 4 elems each
    const int base = i * 4;
    const int d = base & 63, h = (base >> 6) & 7;
    const int bt = base >> 9;              // b*1024 + tok
    const size_t pi = (((size_t)(bt >> 10) * 8 + h) * QT_ + (bt & 1023)) * DH_ + d;
    f32x4 s0 = *reinterpret_cast<const f32x4*>(pvpart + pi);
    f32x4 s1 = *reinterpret_cast<const f32x4*>(pvpart + SL + pi);
    f32x4 s2 = *reinterpret_cast<const f32x4*>(pvpart + 2 * SL + pi);
    f32x4 s3 = *reinterpret_cast<const f32x4*>(pvpart + 3 * SL + pi);
    u16x4 o;
#pragma unroll
    for (int j = 0; j < 4; j++) o[j] = f2bf((s0[j] + s1[j]) + (s2[j] + s3[j]));
    *reinterpret_cast<u16x4*>(ctx + base) = o;
}

// -------------------- O projection: 64x64 tiles, grid 512 --------------------
__global__ __launch_bounds__(256) void proj_o(const u16* __restrict__ X,
                                              const u16* __restrict__ Wt,
                                              const float* __restrict__ bias,
                                              float* __restrict__ outp,
                                              const int* __restrict__ qmask) {
    __shared__ __align__(16) u16 la[2][64 * 64];
    __shared__ __align__(16) u16 lb[2][64 * 64];

    const int id = blockIdx.x;             // 512 blocks
    const int sw = (id & 7) * 64 + (id >> 3);
    const int m0 = (sw >> 3) * 64, n0 = (sw & 7) * 64;

    const int tid = threadIdx.x, w = tid >> 6, lane = tid & 63;
    const int lr = lane & 15, lg = lane >> 4;
    const int wml = (w >> 1) * 32, wnl = (w & 1) * 32;

    auto stage = [&](const u16* gsrc, u16* lbuf) {
#pragma unroll
        for (int i = 0; i < 2; i++) {
            const int r0 = w * 16 + i * 8;
            const int row = r0 + (lane >> 3);
            const u16* src = gsrc + row * E_ + (((lane & 7) ^ (row & 7)) * 8);
            g2lds16(src, lbuf + r0 * 64);
        }
    };

    f32x4 acc[2][2];
#pragma unroll
    for (int i = 0; i < 2; i++)
#pragma unroll
        for (int j = 0; j < 2; j++) acc[i][j] = f32x4{0.f, 0.f, 0.f, 0.f};

    stage(X + m0 * E_, la[0]);
    stage(Wt + n0 * E_, lb[0]);
    __syncthreads();
    int buf = 0;
    for (int kt = 0; kt < E_ / 64; kt++) {
        if (kt + 1 < E_ / 64) {
            stage(X + m0 * E_ + (kt + 1) * 64, la[buf ^ 1]);
            stage(Wt + n0 * E_ + (kt + 1) * 64, lb[buf ^ 1]);
        }
#pragma unroll
        for (int ks = 0; ks < 2; ks++) {
            bf16x8 a[2], bb[2];
#pragma unroll
            for (int mb = 0; mb < 2; mb++) {
                const int r = wml + mb * 16 + lr;
                a[mb] = ldbf8(la[buf] + r * 64 + (((ks * 4 + lg) ^ (r & 7)) * 8));
            }
#pragma unroll
            for (int nb = 0; nb < 2; nb++) {
                const int r = wnl + nb * 16 + lr;
                bb[nb] = ldbf8(lb[buf] + r * 64 + (((ks * 4 + lg) ^ (r & 7)) * 8));
            }
            __builtin_amdgcn_s_setprio(1);
#pragma unroll
            for (int mb = 0; mb < 2; mb++)
#pragma unroll
                for (int nb = 0; nb < 2; nb++)
                    acc[mb][nb] = MFMA16(a[mb], bb[nb], acc[mb][nb]);
            __builtin_amdgcn_s_setprio(0);
        }
        __syncthreads();
        buf ^= 1;
    }

#pragma unroll
    for (int mb = 0; mb < 2; mb++) {
#pragma unroll
        for (int nb = 0; nb < 2; nb++) {
            const int col = n0 + wnl + nb * 16 + lr;
            const float bs = bias[col];
#pragma unroll
            for (int r = 0; r < 4; r++) {
                const int row = m0 + wml + mb * 16 + lg * 4 + r;
                float v = acc[mb][nb][r] + bs;
                float m = (qmask[row] != 0) ? 1.0f : 0.0f;
                outp[row * E_ + col] = v * m;
            }
        }
    }
}

// -------------------- host launch --------------------
extern "C" void kernel_launch(void* const* d_in, const int* in_sizes, int n_in,
                              void* d_out, int out_size, void* d_ws, size_t ws_size,
                              hipStream_t stream) {
    (void)in_sizes; (void)n_in; (void)out_size; (void)ws_size;
    const float* q   = (const float*)d_in[0];
    const float* kv  = (const float*)d_in[1];
    const int* q_mask  = (const int*)d_in[2];
    const int* kv_mask = (const int*)d_in[3];
    const int* q_pos   = (const int*)d_in[4];
    const int* kv_pos  = (const int*)d_in[5];
    const float* Wq = (const float*)d_in[6];  const float* bq = (const float*)d_in[7];
    const float* Wk = (const float*)d_in[8];  const float* bk = (const float*)d_in[9];
    const float* Wv = (const float*)d_in[10]; const float* bv = (const float*)d_in[11];
    const float* Wo = (const float*)d_in[12]; const float* bo = (const float*)d_in[13];
    float* outp = (float*)d_out;

    char* ws = (char*)d_ws;
    size_t off = 0;
    auto carve = [&](size_t bytes) -> void* {
        void* p = ws + off;
        off = (off + bytes + 255) & ~(size_t)255;
        return p;
    };
    u16* qbf    = (u16*)carve((size_t)B_ * QT_ * E_ * 2);
    u16* kvbf   = (u16*)carve((size_t)B_ * N_ * E_ * 2);
    u16* wt4    = (u16*)carve((size_t)4 * E_ * E_ * 2);  // [Wq^T|Wk^T|Wv^T|Wo^T]
    u16* qhh    = (u16*)carve((size_t)B_ * H_ * QT_ * DH_ * 2);
    u16* khh    = (u16*)carve((size_t)B_ * H_ * N_ * DH_ * 2);
    u16* vt     = (u16*)carve((size_t)B_ * H_ * DH_ * N_ * 2);  // tiled [bh][32][64][64]
    u16* ctx    = (u16*)carve((size_t)B_ * QT_ * E_ * 2);
    float2* tq  = (float2*)carve((size_t)B_ * QT_ * 16 * sizeof(float2));
    float2* tk  = (float2*)carve((size_t)B_ * N_ * 16 * sizeof(float2));
    float* sums4  = (float*)carve((size_t)B_ * H_ * QT_ * 4 * sizeof(float));
    float* pvpart = (float*)carve((size_t)4 * B_ * H_ * QT_ * DH_ * sizeof(float));

    prep_all<<<7168, 256, 0, stream>>>(q, kv, Wq, Wk, Wv, Wo, q_pos, kv_pos,
                                       qbf, kvbf, wt4, tq, tk);

    proj_qkv<<<640, 256, 0, stream>>>(qbf, kvbf, wt4, bq, bk, bv, qhh, khh, vt, tq, tk);

    attn_sums<<<2048, 256, 0, stream>>>(qhh, khh, kv_mask, sums4);
    attn_pv<<<512, 512, 0, stream>>>(qhh, khh, vt, kv_mask, sums4,
                                     outp + (size_t)B_ * QT_ * E_, pvpart);
    ctx_reduce<<<2048, 256, 0, stream>>>(pvpart, ctx);

    proj_o<<<512, 256, 0, stream>>>(ctx, wt4 + 3 * 512 * 512, bo, outp, q_mask);
}

// Round 14
// 147.827 us; speedup vs baseline: 1.8981x; 1.0383x over previous
//
#include <hip/hip_runtime.h>
#include <hip/hip_bf16.h>

// Problem constants (CrossEncoder): B=4, QT=1024, N=2048, E=512, H=8, Dh=64
#define B_  4
#define QT_ 1024
#define N_  2048
#define E_  512
#define H_  8
#define DH_ 64

typedef float  f32x4  __attribute__((ext_vector_type(4)));
typedef __bf16 bf16x8 __attribute__((ext_vector_type(8)));
typedef unsigned short u16;
typedef u16 u16x4 __attribute__((ext_vector_type(4)));

// round-to-nearest-even f32 -> bf16
static __device__ __forceinline__ u16 f2bf(float f) {
    unsigned u = __builtin_bit_cast(unsigned, f);
    return (u16)((u + 0x7fffu + ((u >> 16) & 1u)) >> 16);
}

static __device__ __forceinline__ bf16x8 ldbf8(const u16* p) {
    uint4 v = *reinterpret_cast<const uint4*>(p);
    return __builtin_bit_cast(bf16x8, v);
}

#define MFMA16(a, b, c) __builtin_amdgcn_mfma_f32_16x16x32_bf16((a), (b), (c), 0, 0, 0)

// async global->LDS, 16B per lane; LDS dest = uniform base + lane*16 (linear)
static __device__ __forceinline__ void g2lds16(const u16* g, u16* l) {
    __builtin_amdgcn_global_load_lds((__attribute__((address_space(1))) void*)(void*)g,
                                     (__attribute__((address_space(3))) void*)l, 16, 0, 0);
}

// -------------------- fused prep: cvt (6144 blk) + wt (256 blk) + rope (768 blk) --------
__global__ __launch_bounds__(256) void prep_all(const float* __restrict__ q,
                                                const float* __restrict__ kv,
                                                const float* __restrict__ Wq,
                                                const float* __restrict__ Wk,
                                                const float* __restrict__ Wv,
                                                const float* __restrict__ Wo,
                                                const int* __restrict__ qpos,
                                                const int* __restrict__ kvpos,
                                                u16* __restrict__ qbf,
                                                u16* __restrict__ kvbf,
                                                u16* __restrict__ wt4,
                                                float2* __restrict__ tq,
                                                float2* __restrict__ tk) {
    __shared__ float t[64][65];
    const int bid = blockIdx.x, tid = threadIdx.x;
    if (bid < 6144) {
        const int QN4 = B_ * QT_ * E_ / 4;  // 524288
        int i = bid * 256 + tid;
        const float4* s;
        ushort4* d;
        if (i < QN4) {
            s = reinterpret_cast<const float4*>(q) + i;
            d = reinterpret_cast<ushort4*>(qbf) + i;
        } else {
            int j = i - QN4;
            s = reinterpret_cast<const float4*>(kv) + j;
            d = reinterpret_cast<ushort4*>(kvbf) + j;
        }
        float4 v = *s;
        ushort4 o;
        o.x = f2bf(v.x); o.y = f2bf(v.y); o.z = f2bf(v.z); o.w = f2bf(v.w);
        *d = o;
    } else if (bid < 6400) {
        const int idx = bid - 6144;
        const int z = idx >> 6, rem = idx & 63, xb = rem & 7, yb = rem >> 3;
        const float* W = (z == 0) ? Wq : (z == 1) ? Wk : (z == 2) ? Wv : Wo;
        u16* dst = wt4 + (size_t)z * E_ * E_;
        const int k0 = xb * 64, n0 = yb * 64;
#pragma unroll
        for (int i = 0; i < 16; i++) {
            int ix = tid + i * 256, r = ix >> 6, c = ix & 63;
            t[r][c] = W[(k0 + r) * E_ + n0 + c];
        }
        __syncthreads();
#pragma unroll
        for (int i = 0; i < 16; i++) {
            int ix = tid + i * 256, r = ix >> 6, c = ix & 63;
            dst[(n0 + r) * E_ + k0 + c] = f2bf(t[c][r]);
        }
    } else {
        const int QROWS = B_ * QT_;  // 4096
        int i = (bid - 6400) * 256 + tid;  // 196608 total
        int k = i & 15, row = i >> 4;
        float fr = exp2f((float)k * -0.41524101186092028f);  // log2(10000)/32
        int p;
        float2* dst;
        if (row < QROWS) { p = qpos[row]; dst = tq + i; }
        else { p = kvpos[row - QROWS]; dst = tk + (i - QROWS * 16); }
        float sn, cs;
        sincosf((float)p * fr, &sn, &cs);
        *dst = make_float2(cs, sn);
    }
}

// -------------------- fused Q+K+V projection GEMM (BK=32: 32KB LDS, all 640 resident) ----
__global__ __launch_bounds__(256) void proj_qkv(const u16* __restrict__ qbf,
                                                const u16* __restrict__ kvbf,
                                                const u16* __restrict__ wt4,
                                                const float* __restrict__ bq,
                                                const float* __restrict__ bk,
                                                const float* __restrict__ bv,
                                                u16* __restrict__ qhh,
                                                u16* __restrict__ khh,
                                                u16* __restrict__ vt,
                                                const float2* __restrict__ tq,
                                                const float2* __restrict__ tk) {
    __shared__ __align__(16) u16 la[2][128 * 32];
    __shared__ __align__(16) u16 lb[2][128 * 32];

    const int id = blockIdx.x;
    const int sw = (id & 7) * 80 + (id >> 3);  // bijective XCD swizzle over 640
    const bool isQ = (sw < 128);
    int m0, n0;
    const u16 *X, *W;
    if (isQ) { m0 = (sw >> 2) * 128; n0 = (sw & 3) * 128; X = qbf; W = wt4; }
    else { const int s2 = sw - 128; m0 = (s2 >> 3) * 128; n0 = (s2 & 7) * 128; X = kvbf; W = wt4 + 512 * 512; }

    const int tid = threadIdx.x, w = tid >> 6, lane = tid & 63;
    const int lr = lane & 15, lg = lane >> 4;
    const int wml = (w >> 1) * 64, wnl = (w & 1) * 64;

    auto stage = [&](const u16* gsrc, u16* lbuf) {
#pragma unroll
        for (int i = 0; i < 2; i++) {
            const int r0 = w * 32 + i * 16;
            const int row = r0 + (lane >> 2);
            const u16* src = gsrc + row * E_ + (((lane & 3) ^ (row & 3)) * 8);
            g2lds16(src, lbuf + r0 * 32);
        }
    };

    f32x4 acc[4][4];
#pragma unroll
    for (int i = 0; i < 4; i++)
#pragma unroll
        for (int j = 0; j < 4; j++) acc[i][j] = f32x4{0.f, 0.f, 0.f, 0.f};

    stage(X + m0 * E_, la[0]);
    stage(W + n0 * E_, lb[0]);
    __syncthreads();
    int buf = 0;
    for (int kt = 0; kt < E_ / 32; kt++) {
        if (kt + 1 < E_ / 32) {
            stage(X + m0 * E_ + (kt + 1) * 32, la[buf ^ 1]);
            stage(W + n0 * E_ + (kt + 1) * 32, lb[buf ^ 1]);
        }
        bf16x8 a[4], bb[4];
#pragma unroll
        for (int mb = 0; mb < 4; mb++) {
            const int r = wml + mb * 16 + lr;
            a[mb] = ldbf8(la[buf] + r * 32 + ((lg ^ (r & 3)) * 8));
        }
#pragma unroll
        for (int nb = 0; nb < 4; nb++) {
            const int r = wnl + nb * 16 + lr;
            bb[nb] = ldbf8(lb[buf] + r * 32 + ((lg ^ (r & 3)) * 8));
        }
        __builtin_amdgcn_s_setprio(1);
#pragma unroll
        for (int mb = 0; mb < 4; mb++)
#pragma unroll
            for (int nb = 0; nb < 4; nb++)
                acc[mb][nb] = MFMA16(a[mb], bb[nb], acc[mb][nb]);
        __builtin_amdgcn_s_setprio(0);
        __syncthreads();
        buf ^= 1;
    }

    const bool isV = !isQ && (n0 >= 512);  // wg-uniform
#pragma unroll
    for (int mb = 0; mb < 4; mb++) {
#pragma unroll
        for (int nb = 0; nb < 4; nb++) {
            const int col = n0 + wnl + nb * 16 + lr;  // C col = lane&15
            const float bs = isQ ? bq[col] : (isV ? bv[col - 512] : bk[col]);
#pragma unroll
            for (int r = 0; r < 4; r++) {
                const int row = m0 + wml + mb * 16 + lg * 4 + r;  // C row = (lane>>4)*4+reg
                float v = acc[mb][nb][r] + bs;
                if (isV) {
                    const int cv = col - 512, d = cv & 63, h = cv >> 6;
                    const int b = row >> 11, n = row & 2047;
                    vt[(((b * H_ + h) * (N_ / 64) + (n >> 6)) * DH_ + d) * 64 + (n & 63)] = f2bf(v);
                } else {
                    const int d = col & 63, h = col >> 6;
                    float2 t = isQ ? tq[row * 16 + (d >> 2)] : tk[row * 16 + (d >> 2)];
                    float other = __shfl_xor(v, 1);  // pair mate: col^1 lives in lane^1
                    float y = (d & 1) ? (other * t.y + v * t.x) : (v * t.x - other * t.y);
                    if (isQ) {
                        y *= 0.125f;  // softmax scale folded into Q
                        const int b = row >> 10, tok = row & 1023;
                        qhh[((b * H_ + h) * QT_ + tok) * DH_ + d] = f2bf(y);
                    } else {
                        const int b = row >> 11, tok = row & 2047;
                        khh[((b * H_ + h) * N_ + tok) * DH_ + d] = f2bf(y);
                    }
                }
            }
        }
    }
}

// -------------------- attn pass A: partial row sums (8 waves x 32 q-rows) ----------------
// grid 512 (XCD-swizzled): (bh, qt of 4, ns of 4). wg = 512 thr = 8 waves; wave w owns
// q-rows [qt*256 + w*32, +32) as TWO 16-row A-blocks -> K LDS frags read once per 2 blocks.
// K staged via global_load_lds (dbuf 16KB only). Writes sums4[..*4+ns].
__global__ __launch_bounds__(512) void attn_sums(const u16* __restrict__ qh,
                                                 const u16* __restrict__ kh,
                                                 const int* __restrict__ kv_mask,
                                                 float* __restrict__ sums4) {
    __shared__ __align__(16) u16 kbuf[2][64 * 64];

    const int id = blockIdx.x;
    const int sw = (id & 7) * 64 + (id >> 3);   // XCD k gets 4 consecutive bh
    const int bh = sw >> 4, qt = (sw >> 2) & 3, ns = sw & 3;
    const int b = bh >> 3;
    const int tid = threadIdx.x, w = tid >> 6, lane = tid & 63;
    const int lr = lane & 15, lg = lane >> 4;
    const int q0 = qt * 256 + w * 32;

    const u16* qbase = qh + (bh * QT_ + q0) * DH_;
    bf16x8 qf[2][2];
#pragma unroll
    for (int mq = 0; mq < 2; mq++) {
        qf[mq][0] = ldbf8(qbase + (mq * 16 + lr) * DH_ + lg * 8);       // Q pre-scaled
        qf[mq][1] = ldbf8(qbase + (mq * 16 + lr) * DH_ + 32 + lg * 8);
    }
    const u16* kbase = kh + (size_t)bh * (N_ * DH_) + ns * 512 * DH_;
    const int* mbase = kv_mask + b * N_ + ns * 512;

    auto stageK = [&](int t, u16* kb) {
        const int r0 = w * 8;
        const int row = r0 + (lane >> 3);
        const int gsw = ((lane & 7) ^ (row & 7)) * 8;
        g2lds16(kbase + (t * 64 + row) * 64 + gsw, kb + r0 * 64);
    };

    float lsum[2][4] = {{0.f, 0.f, 0.f, 0.f}, {0.f, 0.f, 0.f, 0.f}};
    stageK(0, kbuf[0]);
    __syncthreads();
    for (int t = 0; t < 8; t++) {
        const u16* kc = kbuf[t & 1];
        if (t < 7) stageK(t + 1, kbuf[(t + 1) & 1]);
#pragma unroll
        for (int n = 0; n < 4; n++) {
            const int krow = n * 16 + lr;
            const u16* kp = kc + krow * 64;
            bf16x8 k0 = ldbf8(kp + ((lg ^ (krow & 7)) * 8));
            bf16x8 k1 = ldbf8(kp + (((lg + 4) ^ (krow & 7)) * 8));
            f32x4 c0 = f32x4{0.f, 0.f, 0.f, 0.f};
            f32x4 c1 = f32x4{0.f, 0.f, 0.f, 0.f};
            __builtin_amdgcn_s_setprio(1);
            c0 = MFMA16(qf[0][0], k0, c0);
            c0 = MFMA16(qf[0][1], k1, c0);
            c1 = MFMA16(qf[1][0], k0, c1);
            c1 = MFMA16(qf[1][1], k1, c1);
            __builtin_amdgcn_s_setprio(0);
            const bool keep = (mbase[t * 64 + krow] != 0);
#pragma unroll
            for (int r = 0; r < 4; r++) {
                lsum[0][r] += keep ? __expf(c0[r]) : 0.f;
                lsum[1][r] += keep ? __expf(c1[r]) : 0.f;
            }
        }
        __syncthreads();
    }
#pragma unroll
    for (int mq = 0; mq < 2; mq++)
#pragma unroll
        for (int r = 0; r < 4; r++) {
            float s = lsum[mq][r];
            s += __shfl_xor(s, 1); s += __shfl_xor(s, 2);
            s += __shfl_xor(s, 4); s += __shfl_xor(s, 8);
            if (lr == 0)
                sums4[((size_t)bh * QT_ + q0 + mq * 16 + lg * 4 + r) * 4 + ns] = s;
        }
}

// -------------------- attn pass B: write attn + partial PV (8 waves x 32 q-rows) ----------
// grid 512 (XCD-swizzled): (bh, qt of 4, ns of 4). wg = 512 thr = 8 waves; wave w owns
// q-rows [qt*256 + w*32, +32) as TWO 16-row A-blocks -> K and V LDS fragments are read
// ONCE and reused for both blocks. LDS = 16K Kdbuf + 16K Vdbuf + 32K P = 64KB -> 2 wg/CU.
__global__ __launch_bounds__(512, 4) void attn_pv(const u16* __restrict__ qh,
                                                  const u16* __restrict__ kh,
                                                  const u16* __restrict__ vt,
                                                  const int* __restrict__ kv_mask,
                                                  const float* __restrict__ sums4,
                                                  float* __restrict__ attn_out,
                                                  float* __restrict__ pvpart) {
    __shared__ __align__(16) u16 kbuf[2][64 * 64];
    __shared__ __align__(16) u16 vbuf[2][64 * 64];
    __shared__ unsigned PW[8][32][32];  // per-wave packed bf16-pair P (32 q), granule-swz

    const int id = blockIdx.x;
    const int sw = (id & 7) * 64 + (id >> 3);   // XCD k gets 4 consecutive bh
    const int bh = sw >> 4, qt = (sw >> 2) & 3, ns = sw & 3;
    const int b = bh >> 3;
    const int tid = threadIdx.x, w = tid >> 6, lane = tid & 63;
    const int lr = lane & 15, lg = lane >> 4;
    const int q0 = qt * 256 + w * 32;

    const u16* qbase = qh + (bh * QT_ + q0) * DH_;
    bf16x8 qf[2][2];
#pragma unroll
    for (int mq = 0; mq < 2; mq++) {
        qf[mq][0] = ldbf8(qbase + (mq * 16 + lr) * DH_ + lg * 8);       // Q pre-scaled
        qf[mq][1] = ldbf8(qbase + (mq * 16 + lr) * DH_ + 32 + lg * 8);
    }
    const u16* kbase = kh + (size_t)bh * (N_ * DH_) + ns * 512 * DH_;
    const u16* vbase = vt + (size_t)bh * (N_ * DH_) + ns * 512 * DH_;  // [8 t][64 d][64]
    const int* mbase = kv_mask + b * N_ + ns * 512;

    // total row sums -> inv
    float inv[2][4];
#pragma unroll
    for (int mq = 0; mq < 2; mq++)
#pragma unroll
        for (int r = 0; r < 4; r++) {
            float4 s4 = *reinterpret_cast<const float4*>(
                sums4 + ((size_t)bh * QT_ + q0 + mq * 16 + lg * 4 + r) * 4);
            float tot = s4.x + s4.y + s4.z + s4.w;
            inv[mq][r] = (tot > 0.f) ? (1.0f / tot) : 0.f;  // all-masked -> attn = ctx = 0
        }

    // stage K tile [64 kv][64 d] + V tile [64 d][64 kv]: wave w stages rows [w*8, w*8+8)
    auto stage = [&](int t, u16* kb, u16* vb) {
        const int r0 = w * 8;
        const int row = r0 + (lane >> 3);
        const int gsw = ((lane & 7) ^ (row & 7)) * 8;
        g2lds16(kbase + (t * 64 + row) * 64 + gsw, kb + r0 * 64);
        g2lds16(vbase + (t * 64 + row) * 64 + gsw, vb + r0 * 64);
    };

    f32x4 pv[2][4];
#pragma unroll
    for (int mq = 0; mq < 2; mq++)
#pragma unroll
        for (int i = 0; i < 4; i++) pv[mq][i] = f32x4{0.f, 0.f, 0.f, 0.f};
    unsigned(*P)[32] = PW[w];
    float* abase = attn_out + ((size_t)(bh * QT_ + q0)) * N_ + ns * 512;
    const int srow = lane >> 4, cq = lane & 15;  // store: 4 rows x 256B per instr

    stage(0, kbuf[0], vbuf[0]);
    __syncthreads();
    for (int t = 0; t < 8; t++) {
        const u16* kc = kbuf[t & 1];
        const u16* vc = vbuf[t & 1];
        if (t < 7) stage(t + 1, kbuf[(t + 1) & 1], vbuf[(t + 1) & 1]);
#pragma unroll
        for (int n = 0; n < 4; n++) {
            const int krow = n * 16 + lr;
            const u16* kp = kc + krow * 64;
            bf16x8 k0 = ldbf8(kp + ((lg ^ (krow & 7)) * 8));
            bf16x8 k1 = ldbf8(kp + (((lg + 4) ^ (krow & 7)) * 8));
            f32x4 c0 = f32x4{0.f, 0.f, 0.f, 0.f};
            f32x4 c1 = f32x4{0.f, 0.f, 0.f, 0.f};
            __builtin_amdgcn_s_setprio(1);
            c0 = MFMA16(qf[0][0], k0, c0);
            c0 = MFMA16(qf[0][1], k1, c0);
            c1 = MFMA16(qf[1][0], k0, c1);
            c1 = MFMA16(qf[1][1], k1, c1);
            __builtin_amdgcn_s_setprio(0);
            const bool keep = (mbase[t * 64 + krow] != 0);
#pragma unroll
            for (int mq = 0; mq < 2; mq++) {
#pragma unroll
                for (int r = 0; r < 4; r++) {
                    float p = keep ? (__expf((mq ? c1 : c0)[r]) * inv[mq][r]) : 0.f;
                    float hi = __shfl_xor(p, 1);
                    __bf16 lo_b = (__bf16)p, hi_b = (__bf16)hi;
                    unsigned pk = ((unsigned)__builtin_bit_cast(u16, hi_b) << 16) |
                                  (unsigned)__builtin_bit_cast(u16, lo_b);
                    if (!(lr & 1)) {
                        const int row = mq * 16 + lg * 4 + r, c32 = n * 8 + (lr >> 1);
                        P[row][(((c32 >> 2) ^ (row & 7)) << 2) + (c32 & 3)] = pk;
                    }
                }
            }
        }
        // attn stores: read packed P (b64), unpack bf16->f32, 4 rows x 256B segments
#pragma unroll
        for (int i = 0; i < 8; i++) {
            const int row = i * 4 + srow, rw = row & 7;
            const int m = (((cq >> 1) ^ rw) << 2) + ((cq & 1) << 1);
            uint2 pp = *reinterpret_cast<const uint2*>(&P[row][m]);
            f32x4 vv;
            vv[0] = __builtin_bit_cast(float, pp.x << 16);
            vv[1] = __builtin_bit_cast(float, pp.x & 0xffff0000u);
            vv[2] = __builtin_bit_cast(float, pp.y << 16);
            vv[3] = __builtin_bit_cast(float, pp.y & 0xffff0000u);
            *reinterpret_cast<f32x4*>(abase + (size_t)row * N_ + t * 64 + cq * 4) = vv;
        }
        // PV: ctx[32q,64d] += P @ V-tile; V b128 frags loaded once, reused for both mq
#pragma unroll
        for (int ks = 0; ks < 2; ks++) {
            bf16x8 bv[4];
#pragma unroll
            for (int nb = 0; nb < 4; nb++) {
                const int vrow = nb * 16 + lr;
                bv[nb] = ldbf8(vc + vrow * 64 + (((ks * 4 + lg) ^ (vrow & 7)) * 8));
            }
            const int g = (4 * ks + lg) ^ (lr & 7);
#pragma unroll
            for (int mq = 0; mq < 2; mq++) {
                uint4 a4 = *reinterpret_cast<const uint4*>(&P[mq * 16 + lr][g << 2]);
                bf16x8 af = __builtin_bit_cast(bf16x8, a4);
                __builtin_amdgcn_s_setprio(1);
#pragma unroll
                for (int nb = 0; nb < 4; nb++)
                    pv[mq][nb] = MFMA16(af, bv[nb], pv[mq][nb]);
                __builtin_amdgcn_s_setprio(0);
            }
        }
        __syncthreads();
    }

    // partial ctx: pvpart[ns][bh][q][64]
    float* pbase = pvpart + (((size_t)ns * 32 + bh) * QT_) * DH_;
#pragma unroll
    for (int mq = 0; mq < 2; mq++)
#pragma unroll
        for (int nb = 0; nb < 4; nb++)
#pragma unroll
            for (int r = 0; r < 4; r++)
                pbase[(size_t)(q0 + mq * 16 + lg * 4 + r) * DH_ + nb * 16 + lr] = pv[mq][nb][r];
}

// -------------------- ctx reduce: ctx[b,tok,h*64+d] = bf16(sum_ns pvpart) ------------
__global__ __launch_bounds__(256) void ctx_reduce(const float* __restrict__ pvpart,
                                                  u16* __restrict__ ctx) {
    const size_t SL = (size_t)32 * QT_ * DH_;  // slice stride (f32)
    const int i = blockIdx.x * 256 + threadIdx.x;  // 524288 threads, 4 elems each
    const int base = i * 4;
    const int d = base & 63, h = (base >> 6) & 7;
    const int bt = base >> 9;              // b*1024 + tok
    const size_t pi = (((size_t)(bt >> 10) * 8 + h) * QT_ + (bt & 1023)) * DH_ + d;
    f32x4 s0 = *reinterpret_cast<const f32x4*>(pvpart + pi);
    f32x4 s1 = *reinterpret_cast<const f32x4*>(pvpart + SL + pi);
    f32x4 s2 = *reinterpret_cast<const f32x4*>(pvpart + 2 * SL + pi);
    f32x4 s3 = *reinterpret_cast<const f32x4*>(pvpart + 3 * SL + pi);
    u16x4 o;
#pragma unroll
    for (int j = 0; j < 4; j++) o[j] = f2bf((s0[j] + s1[j]) + (s2[j] + s3[j]));
    *reinterpret_cast<u16x4*>(ctx + base) = o;
}

// -------------------- O projection: 64x64 tiles, grid 512 --------------------
__global__ __launch_bounds__(256) void proj_o(const u16* __restrict__ X,
                                              const u16* __restrict__ Wt,
                                              const float* __restrict__ bias,
                                              float* __restrict__ outp,
                                              const int* __restrict__ qmask) {
    __shared__ __align__(16) u16 la[2][64 * 64];
    __shared__ __align__(16) u16 lb[2][64 * 64];

    const int id = blockIdx.x;             // 512 blocks
    const int sw = (id & 7) * 64 + (id >> 3);
    const int m0 = (sw >> 3) * 64, n0 = (sw & 7) * 64;

    const int tid = threadIdx.x, w = tid >> 6, lane = tid & 63;
    const int lr = lane & 15, lg = lane >> 4;
    const int wml = (w >> 1) * 32, wnl = (w & 1) * 32;

    auto stage = [&](const u16* gsrc, u16* lbuf) {
#pragma unroll
        for (int i = 0; i < 2; i++) {
            const int r0 = w * 16 + i * 8;
            const int row = r0 + (lane >> 3);
            const u16* src = gsrc + row * E_ + (((lane & 7) ^ (row & 7)) * 8);
            g2lds16(src, lbuf + r0 * 64);
        }
    };

    f32x4 acc[2][2];
#pragma unroll
    for (int i = 0; i < 2; i++)
#pragma unroll
        for (int j = 0; j < 2; j++) acc[i][j] = f32x4{0.f, 0.f, 0.f, 0.f};

    stage(X + m0 * E_, la[0]);
    stage(Wt + n0 * E_, lb[0]);
    __syncthreads();
    int buf = 0;
    for (int kt = 0; kt < E_ / 64; kt++) {
        if (kt + 1 < E_ / 64) {
            stage(X + m0 * E_ + (kt + 1) * 64, la[buf ^ 1]);
            stage(Wt + n0 * E_ + (kt + 1) * 64, lb[buf ^ 1]);
        }
#pragma unroll
        for (int ks = 0; ks < 2; ks++) {
            bf16x8 a[2], bb[2];
#pragma unroll
            for (int mb = 0; mb < 2; mb++) {
                const int r = wml + mb * 16 + lr;
                a[mb] = ldbf8(la[buf] + r * 64 + (((ks * 4 + lg) ^ (r & 7)) * 8));
            }
#pragma unroll
            for (int nb = 0; nb < 2; nb++) {
                const int r = wnl + nb * 16 + lr;
                bb[nb] = ldbf8(lb[buf] + r * 64 + (((ks * 4 + lg) ^ (r & 7)) * 8));
            }
            __builtin_amdgcn_s_setprio(1);
#pragma unroll
            for (int mb = 0; mb < 2; mb++)
#pragma unroll
                for (int nb = 0; nb < 2; nb++)
                    acc[mb][nb] = MFMA16(a[mb], bb[nb], acc[mb][nb]);
            __builtin_amdgcn_s_setprio(0);
        }
        __syncthreads();
        buf ^= 1;
    }

#pragma unroll
    for (int mb = 0; mb < 2; mb++) {
#pragma unroll
        for (int nb = 0; nb < 2; nb++) {
            const int col = n0 + wnl + nb * 16 + lr;
            const float bs = bias[col];
#pragma unroll
            for (int r = 0; r < 4; r++) {
                const int row = m0 + wml + mb * 16 + lg * 4 + r;
                float v = acc[mb][nb][r] + bs;
                float m = (qmask[row] != 0) ? 1.0f : 0.0f;
                outp[row * E_ + col] = v * m;
            }
        }
    }
}

// -------------------- host launch --------------------
extern "C" void kernel_launch(void* const* d_in, const int* in_sizes, int n_in,
                              void* d_out, int out_size, void* d_ws, size_t ws_size,
                              hipStream_t stream) {
    (void)in_sizes; (void)n_in; (void)out_size; (void)ws_size;
    const float* q   = (const float*)d_in[0];
    const float* kv  = (const float*)d_in[1];
    const int* q_mask  = (const int*)d_in[2];
    const int* kv_mask = (const int*)d_in[3];
    const int* q_pos   = (const int*)d_in[4];
    const int* kv_pos  = (const int*)d_in[5];
    const float* Wq = (const float*)d_in[6];  const float* bq = (const float*)d_in[7];
    const float* Wk = (const float*)d_in[8];  const float* bk = (const float*)d_in[9];
    const float* Wv = (const float*)d_in[10]; const float* bv = (const float*)d_in[11];
    const float* Wo = (const float*)d_in[12]; const float* bo = (const float*)d_in[13];
    float* outp = (float*)d_out;

    char* ws = (char*)d_ws;
    size_t off = 0;
    auto carve = [&](size_t bytes) -> void* {
        void* p = ws + off;
        off = (off + bytes + 255) & ~(size_t)255;
        return p;
    };
    u16* qbf    = (u16*)carve((size_t)B_ * QT_ * E_ * 2);
    u16* kvbf   = (u16*)carve((size_t)B_ * N_ * E_ * 2);
    u16* wt4    = (u16*)carve((size_t)4 * E_ * E_ * 2);  // [Wq^T|Wk^T|Wv^T|Wo^T]
    u16* qhh    = (u16*)carve((size_t)B_ * H_ * QT_ * DH_ * 2);
    u16* khh    = (u16*)carve((size_t)B_ * H_ * N_ * DH_ * 2);
    u16* vt     = (u16*)carve((size_t)B_ * H_ * DH_ * N_ * 2);  // tiled [bh][32][64][64]
    u16* ctx    = (u16*)carve((size_t)B_ * QT_ * E_ * 2);
    float2* tq  = (float2*)carve((size_t)B_ * QT_ * 16 * sizeof(float2));
    float2* tk  = (float2*)carve((size_t)B_ * N_ * 16 * sizeof(float2));
    float* sums4  = (float*)carve((size_t)B_ * H_ * QT_ * 4 * sizeof(float));
    float* pvpart = (float*)carve((size_t)4 * B_ * H_ * QT_ * DH_ * sizeof(float));

    prep_all<<<7168, 256, 0, stream>>>(q, kv, Wq, Wk, Wv, Wo, q_pos, kv_pos,
                                       qbf, kvbf, wt4, tq, tk);

    proj_qkv<<<640, 256, 0, stream>>>(qbf, kvbf, wt4, bq, bk, bv, qhh, khh, vt, tq, tk);

    attn_sums<<<512, 512, 0, stream>>>(qhh, khh, kv_mask, sums4);
    attn_pv<<<512, 512, 0, stream>>>(qhh, khh, vt, kv_mask, sums4,
                                     outp + (size_t)B_ * QT_ * E_, pvpart);
    ctx_reduce<<<2048, 256, 0, stream>>>(pvpart, ctx);

    proj_o<<<512, 256, 0, stream>>>(ctx, wt4 + 3 * 512 * 512, bo, outp, q_mask);
}